// Round 3
// baseline (4438.967 us; speedup 1.0000x reference)
//
#include <hip/hip_runtime.h>
#include <math.h>

#define S_   56
#define B_   32
#define C_   1024
#define T_   48
#define TS   47
#define H_   1024
#define EMB_ 512
#define RANK_ 128
#define VOCAB_ 32000
#define G4   4096
#define NBLK 128

using bf16x8 = __attribute__((ext_vector_type(8))) __bf16;
using f32x4  = __attribute__((ext_vector_type(4))) float;

__device__ __forceinline__ float sigmoidf_(float x){ return 1.0f/(1.0f+expf(-x)); }
__device__ __forceinline__ float b2f(__bf16 x){ return (float)x; }

// ---------------- shared-memory union for the persistent kernel ----------------
struct GemmShared {
  __bf16 As[2][2][32][40];   // [buf][khalf][m][k(+pad)]
  float  Gp[2][32][17];
  float  Gs[32][33];
};
struct AttnShared {
  float hS[1024];
  float sS[64];
  float pS[64];
  float cred[128][8];
};
union alignas(16) SharedU { GemmShared g; AttnShared a; };

// ---------------- grid barrier (monotonic counter, agent scope) ----------------
__device__ __forceinline__ void grid_bar(unsigned* bar, unsigned target){
  __syncthreads();
  if (threadIdx.x == 0){
    __hip_atomic_fetch_add(bar, 1u, __ATOMIC_ACQ_REL, __HIP_MEMORY_SCOPE_AGENT);
    while (__hip_atomic_load(bar, __ATOMIC_ACQUIRE, __HIP_MEMORY_SCOPE_AGENT) < target)
      __builtin_amdgcn_s_sleep(2);
    __threadfence();
  }
  __syncthreads();
}

// ---------------- init ----------------
__global__ void k_init(const float* __restrict__ es, __bf16* xa0a, __bf16* xa1a,
                       float* c0, float* c1, unsigned* bar){
  int i = blockIdx.x*blockDim.x + threadIdx.x;
  if (i < 32*H_){
    int b = i >> 10, j = i & 1023;
    xa0a[(size_t)b*2560 + 1536 + j] = (__bf16)es[i];           // h0 <- es[0]
    xa0a[(size_t)b*2560 + 512  + j] = (__bf16)0.0f;            // ctx = 0
    xa1a[(size_t)b*2048 + 1024 + j] = (__bf16)es[32*H_ + i];   // h1 <- es[1]
    c0[i] = 0.f; c1[i] = 0.f;
  }
  if (blockIdx.x == 0 && threadIdx.x == 0) bar[0] = 0u;
}

// ---------------- fp32 -> bf16 ----------------
__global__ void k_cvt(const float* __restrict__ src, __bf16* __restrict__ dst, int n){
  int i = (blockIdx.x*blockDim.x + threadIdx.x)*4;
  if (i < n){
    float4 v = *(const float4*)(src + i);
    dst[i+0]=(__bf16)v.x; dst[i+1]=(__bf16)v.y; dst[i+2]=(__bf16)v.z; dst[i+3]=(__bf16)v.w;
  }
}

// ---------------- embedding ----------------
__global__ void k_embed(const float* __restrict__ E, const float* __restrict__ P,
                        const int* __restrict__ tok, __bf16* __restrict__ embb,
                        __bf16* __restrict__ xa0a){
  int blk = blockIdx.x;            // t*32+b
  int t = blk >> 5, b = blk & 31, tid = threadIdx.x;   // 128 threads
  __shared__ float er[RANK_];
  int tk = tok[b*T_ + t];
  er[tid] = E[(size_t)tk*RANK_ + tid];
  __syncthreads();
  float4 acc = {0.f,0.f,0.f,0.f};
  int e = tid*4;
  for (int r2 = 0; r2 < RANK_; r2++){
    float ev = er[r2];
    float4 p = *(const float4*)(P + (size_t)r2*EMB_ + e);
    acc.x += ev*p.x; acc.y += ev*p.y; acc.z += ev*p.z; acc.w += ev*p.w;
  }
  size_t o = (size_t)blk*EMB_ + e;
  embb[o+0]=(__bf16)acc.x; embb[o+1]=(__bf16)acc.y;
  embb[o+2]=(__bf16)acc.z; embb[o+3]=(__bf16)acc.w;
  if (t == 0){
    size_t o2 = (size_t)b*2560 + e;
    xa0a[o2+0]=(__bf16)acc.x; xa0a[o2+1]=(__bf16)acc.y;
    xa0a[o2+2]=(__bf16)acc.z; xa0a[o2+3]=(__bf16)acc.w;
  }
}

// ---------------- pack [W;U] into MFMA B-fragment order ----------------
__global__ void k_pack(const float* __restrict__ W, int K1, const float* __restrict__ U,
                       __bf16* __restrict__ dst, int KH, int NCH){
  int kk0 = blockIdx.x*32, j0 = blockIdx.y*64, tid = threadIdx.x;
  __shared__ __bf16 Tl[32][72];
  {
    int r = tid>>3, cp = tid&7;
    int kk = kk0 + r;
    const float* src = (kk < K1) ? (W + (size_t)kk*G4 + j0 + cp*8)
                                 : (U + (size_t)(kk-K1)*G4 + j0 + cp*8);
    float4 v0 = *(const float4*)(src);
    float4 v1 = *(const float4*)(src+4);
    Tl[r][cp*8+0]=(__bf16)v0.x; Tl[r][cp*8+1]=(__bf16)v0.y;
    Tl[r][cp*8+2]=(__bf16)v0.z; Tl[r][cp*8+3]=(__bf16)v0.w;
    Tl[r][cp*8+4]=(__bf16)v1.x; Tl[r][cp*8+5]=(__bf16)v1.y;
    Tl[r][cp*8+6]=(__bf16)v1.z; Tl[r][cp*8+7]=(__bf16)v1.w;
  }
  __syncthreads();
  int jl = tid&63, q = tid>>6;
  __bf16 out8[8];
  #pragma unroll
  for (int i=0;i<8;i++) out8[i] = Tl[q*8+i][jl];
  int j = j0 + jl;
  int g = j>>10, gp = g>>1, gbit = g&1;
  int bi = (j&1023)>>3, jlo = j&7;
  int kh = kk0 / KH, ch = (kk0 % KH) >> 5;
  int lane = q*16 + gbit*8 + jlo;
  size_t off = ((((size_t)(bi*2+gp)*2 + kh)*NCH + ch)*64 + lane)*8;
  *(bf16x8*)(dst + off) = *(bf16x8*)out8;
}

// ---------------- fused gates GEMM + LSTM cell (device fn) ----------------
template<int K, int NCH>
__device__ __forceinline__ void gemm_cell(GemmShared& sgm, int bi, int tid,
    const __bf16* __restrict__ xa_in, const __bf16* __restrict__ WP,
    const float* __restrict__ bias, float* __restrict__ cst,
    __bf16* __restrict__ hout0, int stride0, int off0,
    __bf16* __restrict__ hout1, int stride1, int off1,
    float* __restrict__ houtf, int stridef, int offf)
{
  constexpr int KH = K/2;
  int w = tid>>6, lane = tid&63;
  int gp = w&1, kh = w>>1;
  f32x4 acc0 = {0,0,0,0}, acc1 = {0,0,0,0};

  int sm = (tid>>2)&31, sp = tid&3, skh = tid>>7;
  const __bf16* aptr = xa_in + (size_t)sm*K + skh*KH + sp*8;
  const __bf16* bptr = WP + ((((size_t)bi*2 + gp)*2 + kh)*NCH)*512 + lane*8;
  int am = lane&15, aq = lane>>4;

  bf16x8 sreg[4], breg[4];
  #pragma unroll
  for (int i=0;i<4;i++){
    sreg[i] = *(const bf16x8*)(aptr + (size_t)i*32);
    breg[i] = *(const bf16x8*)(bptr + (size_t)i*512);
  }

  int buf = 0;
  #pragma unroll 4
  for (int ch = 0; ch < NCH; ch++){
    int slot = ch & 3;
    *(bf16x8*)(&sgm.As[buf][skh][sm][sp*8]) = sreg[slot];
    __syncthreads();
    bf16x8 bcur = breg[slot];
    if (ch + 4 < NCH){
      sreg[slot] = *(const bf16x8*)(aptr + (size_t)(ch+4)*32);
      breg[slot] = *(const bf16x8*)(bptr + (size_t)(ch+4)*512);
    }
    bf16x8 a0 = *(const bf16x8*)(&sgm.As[buf][kh][am][aq*8]);
    bf16x8 a1 = *(const bf16x8*)(&sgm.As[buf][kh][am+16][aq*8]);
    acc0 = __builtin_amdgcn_mfma_f32_16x16x32_bf16(a0, bcur, acc0, 0, 0, 0);
    acc1 = __builtin_amdgcn_mfma_f32_16x16x32_bf16(a1, bcur, acc1, 0, 0, 0);
    buf ^= 1;
  }
  __syncthreads();
  if (kh == 1){
    #pragma unroll
    for (int rg=0; rg<4; rg++){
      sgm.Gp[gp][aq*4+rg][am]    = acc0[rg];
      sgm.Gp[gp][16+aq*4+rg][am] = acc1[rg];
    }
  }
  __syncthreads();
  if (kh == 0){
    #pragma unroll
    for (int rg=0; rg<4; rg++){
      sgm.Gs[aq*4+rg][gp*16+am]    = acc0[rg] + sgm.Gp[gp][aq*4+rg][am];
      sgm.Gs[16+aq*4+rg][gp*16+am] = acc1[rg] + sgm.Gp[gp][16+aq*4+rg][am];
    }
  }
  __syncthreads();
  int b = tid>>3, hd = tid&7;
  int j = bi*8 + hd;
  float gi = sgm.Gs[b][hd]     + bias[j];
  float gf = sgm.Gs[b][8+hd]   + bias[1024 + j];
  float gg = sgm.Gs[b][16+hd]  + bias[2048 + j];
  float go = sgm.Gs[b][24+hd]  + bias[3072 + j];
  float ii = sigmoidf_(gi), ff = sigmoidf_(gf), gv = tanhf(gg), oo = sigmoidf_(go);
  float cv = ff*cst[b*1024 + j] + ii*gv;
  float hv = oo*tanhf(cv);
  cst[b*1024 + j] = cv;
  hout0[(size_t)b*stride0 + off0 + j] = (__bf16)hv;
  if (hout1) hout1[(size_t)b*stride1 + off1 + j] = (__bf16)hv;
  if (houtf) houtf[(size_t)b*stridef + offf + j] = hv;
}

// ---------------- attention for one batch row (device fn) ----------------
__device__ __forceinline__ void attn_block(AttnShared& sa, int b, int tid,
    const __bf16* __restrict__ encb, const int* __restrict__ enc_lens,
    float* __restrict__ featst, __bf16* __restrict__ xa0q,
    const __bf16* __restrict__ embnext)
{
  #pragma unroll
  for (int i=0;i<4;i++) sa.hS[tid + i*256] = featst[(size_t)b*2048 + tid + i*256];
  __syncthreads();
  int wv = tid >> 6, lane = tid & 63;
  for (int s = wv; s < S_; s += 4){
    const __bf16* er = encb + ((size_t)s*32 + b)*C_;
    float a = 0.f;
    #pragma unroll
    for (int half = 0; half < 2; half++){
      int k = lane*8 + half*512;
      bf16x8 e8 = *(const bf16x8*)(er + k);
      #pragma unroll
      for (int u=0;u<8;u++) a += b2f(e8[u]) * sa.hS[k+u];
    }
    #pragma unroll
    for (int off=32; off>0; off>>=1) a += __shfl_down(a, off);
    if (lane == 0) sa.sS[s] = a;
  }
  __syncthreads();
  if (tid < 64){
    int len = enc_lens[b];
    float sc = (tid < len && tid < S_) ? sa.sS[tid] : -1e30f;
    float m = sc;
    #pragma unroll
    for (int off=32; off>0; off>>=1) m = fmaxf(m, __shfl_xor(m, off));
    float e = expf(sc - m);
    float ssum = e;
    #pragma unroll
    for (int off=32; off>0; off>>=1) ssum += __shfl_xor(ssum, off);
    sa.pS[tid] = e / ssum;
  }
  __syncthreads();
  int cg = tid & 127, sg2 = tid >> 7;
  float a8[8];
  #pragma unroll
  for (int i=0;i<8;i++) a8[i] = 0.f;
  for (int s = sg2; s < S_; s += 2){
    float p = sa.pS[s];
    bf16x8 e8 = *(const bf16x8*)(encb + ((size_t)s*32 + b)*C_ + cg*8);
    #pragma unroll
    for (int i=0;i<8;i++) a8[i] += p * b2f(e8[i]);
  }
  if (sg2 == 1){
    #pragma unroll
    for (int i=0;i<8;i++) sa.cred[cg][i] = a8[i];
  }
  __syncthreads();
  if (sg2 == 0){
    #pragma unroll
    for (int i=0;i<8;i++){
      float v = a8[i] + sa.cred[cg][i];
      xa0q[(size_t)b*2560 + 512 + cg*8 + i] = (__bf16)v;
      featst[(size_t)b*2048 + 1024 + cg*8 + i] = v;
    }
  }
  if (embnext && tid < 64){
    *(bf16x8*)(xa0q + (size_t)b*2560 + tid*8) =
      *(const bf16x8*)(embnext + (size_t)b*512 + tid*8);
  }
}

// ---------------- persistent decode loop ----------------
__global__ __launch_bounds__(256) void k_loop(
    const __bf16* __restrict__ WP0, const __bf16* __restrict__ WP1,
    const float* __restrict__ b0, const float* __restrict__ b1,
    float* __restrict__ c0, float* __restrict__ c1,
    __bf16* xa0a, __bf16* xa0b, __bf16* xa1a, __bf16* xa1b,
    const __bf16* __restrict__ encb, const int* __restrict__ enc_lens,
    const __bf16* __restrict__ embb, float* __restrict__ feats,
    unsigned* bar)
{
  __shared__ SharedU su;
  int bi = blockIdx.x, tid = threadIdx.x;
  unsigned bcount = 0;
  __bf16* xa0[2] = {xa0a, xa0b};
  __bf16* xa1[2] = {xa1a, xa1b};

  for (int t = 0; t < TS; t++){
    int p = t & 1, q = p ^ 1;
    gemm_cell<2560,40>(su.g, bi, tid, xa0[p], WP0, b0, c0,
                       xa1[p], 2048, 0,
                       xa0[q], 2560, 1536,
                       (float*)nullptr, 0, 0);
    grid_bar(bar, NBLK*(++bcount));
    gemm_cell<2048,32>(su.g, bi, tid, xa1[p], WP1, b1, c1,
                       xa1[q], 2048, 1024,
                       (__bf16*)nullptr, 0, 0,
                       feats + (size_t)t*32*2048, 2048, 0);
    grid_bar(bar, NBLK*(++bcount));
    if (bi < 32)
      attn_block(su.a, bi, tid, encb, enc_lens, feats + (size_t)t*32*2048,
                 xa0[q], (t+1 < TS) ? (embb + (size_t)(t+1)*32*EMB_) : (const __bf16*)nullptr);
    grid_bar(bar, NBLK*(++bcount));
  }
}

// ---------------- hproj = tanh(feats @ Wo + bo) ----------------
__global__ void k_hproj(const float* __restrict__ feats, const float* __restrict__ Wo,
                        const float* __restrict__ bo, float* __restrict__ hp){
  int nt = blockIdx.x, jt = blockIdx.y, tid = threadIdx.x;
  __shared__ float Fs[32][36];
  __shared__ float Ws[32*128];
  int jg = tid & 31, bg = tid >> 5;
  float4 acc[4];
  #pragma unroll
  for (int i=0;i<4;i++) acc[i] = make_float4(0.f,0.f,0.f,0.f);
  for (int kc = 0; kc < 2048; kc += 32){
    { int b = tid & 31, kq = tid >> 5;
      *(float4*)(&Fs[b][kq*4]) =
        *(const float4*)(feats + ((size_t)nt*32 + b)*2048 + kc + kq*4); }
    #pragma unroll
    for (int i2=0;i2<4;i2++){
      int idx = i2*256 + tid;
      int k = idx >> 5, jq = idx & 31;
      *(float4*)(&Ws[k*128 + jq*4]) =
        *(const float4*)(Wo + (size_t)(kc + k)*EMB_ + jt*128 + jq*4);
    }
    __syncthreads();
    #pragma unroll
    for (int k=0;k<32;k++){
      float4 w4 = *(const float4*)(&Ws[k*128 + jg*4]);
      #pragma unroll
      for (int i=0;i<4;i++){
        float xv = Fs[bg*4 + i][k];
        acc[i].x += xv*w4.x; acc[i].y += xv*w4.y;
        acc[i].z += xv*w4.z; acc[i].w += xv*w4.w;
      }
    }
    __syncthreads();
  }
  float4 b4 = *(const float4*)(bo + jt*128 + jg*4);
  #pragma unroll
  for (int i=0;i<4;i++){
    int b = bg*4 + i;
    float4 v;
    v.x = tanhf(acc[i].x + b4.x); v.y = tanhf(acc[i].y + b4.y);
    v.z = tanhf(acc[i].z + b4.z); v.w = tanhf(acc[i].w + b4.w);
    *(float4*)(hp + ((size_t)nt*32 + b)*EMB_ + jt*128 + jg*4) = v;
  }
}

// ---------------- r = hproj @ P^T  (bf16 out) ----------------
__global__ void k_rproj(const float* __restrict__ hp, const float* __restrict__ P,
                        __bf16* __restrict__ rb){
  int n = blockIdx.x, tid = threadIdx.x;   // 1504 x 128
  __shared__ float hS[EMB_];
  *(float4*)(hS + tid*4) = *(const float4*)(hp + (size_t)n*EMB_ + tid*4);
  __syncthreads();
  float a = 0.f;
  for (int e = 0; e < EMB_; e += 4){
    float4 p4 = *(const float4*)(P + (size_t)tid*EMB_ + e);
    a += p4.x*hS[e] + p4.y*hS[e+1] + p4.z*hS[e+2] + p4.w*hS[e+3];
  }
  rb[(size_t)n*RANK_ + tid] = (__bf16)a;
}

// ---------------- vocab GEMM (MFMA bf16) + online LSE partials ----------------
// grid (47 n-tiles of 32, 250 v-chunks of 128), block 256 = 4 waves (h, vq)
__global__ __launch_bounds__(256) void k_vocab_mfma(
    const __bf16* __restrict__ rb, const __bf16* __restrict__ Eb,
    const int* __restrict__ tok,
    float* __restrict__ mpart, float* __restrict__ lpart,
    float* __restrict__ lablog)
{
  int nt = blockIdx.x, vc = blockIdx.y, tid = threadIdx.x;
  int w = tid>>6, lane = tid&63;
  int h = w&1, vq = w>>1;
  int am = lane&15, aq = lane>>4;
  const __bf16* aptr = rb + ((size_t)(nt*32 + h*16 + am))*RANK_ + aq*8;
  int vbase = vc*128 + vq*64;
  f32x4 acc[4] = {{0,0,0,0},{0,0,0,0},{0,0,0,0},{0,0,0,0}};
  #pragma unroll
  for (int ks=0; ks<4; ks++){
    bf16x8 a = *(const bf16x8*)(aptr + ks*32);
    #pragma unroll
    for (int vt=0; vt<4; vt++){
      bf16x8 b8 = *(const bf16x8*)(Eb + ((size_t)(vbase + vt*16 + am))*RANK_ + ks*32 + aq*8);
      acc[vt] = __builtin_amdgcn_mfma_f32_16x16x32_bf16(a, b8, acc[vt], 0, 0, 0);
    }
  }
  __shared__ float redM[2][2][16], redL[2][2][16];
  #pragma unroll
  for (int rg=0; rg<4; rg++){
    int nl = h*16 + aq*4 + rg;
    int n  = nt*32 + nl;
    int lbl = tok[nl*T_ + nt + 1];   // b = nl, predicting token nt+1
    float m4 = -1e30f;
    #pragma unroll
    for (int vt=0; vt<4; vt++){
      float v = acc[vt][rg];
      if (vbase + vt*16 + am == lbl) lablog[n] = v;
      m4 = fmaxf(m4, v);
    }
    float M = m4;
    #pragma unroll
    for (int off=1; off<16; off<<=1) M = fmaxf(M, __shfl_xor(M, off));
    float l = 0.f;
    #pragma unroll
    for (int vt=0; vt<4; vt++) l += expf(acc[vt][rg] - M);
    #pragma unroll
    for (int off=1; off<16; off<<=1) l += __shfl_xor(l, off);
    if (am == 0){ redM[h][vq][aq*4+rg] = M; redL[h][vq][aq*4+rg] = l; }
  }
  __syncthreads();
  if (tid < 32){
    int hh = tid>>4, nl16 = tid&15;
    float M0 = redM[hh][0][nl16], M1 = redM[hh][1][nl16];
    float M = fmaxf(M0, M1);
    float L = redL[hh][0][nl16]*expf(M0-M) + redL[hh][1][nl16]*expf(M1-M);
    int n = nt*32 + hh*16 + nl16;
    mpart[(size_t)n*250 + vc] = M;
    lpart[(size_t)n*250 + vc] = L;
  }
}

// ---------------- final loss ----------------
__global__ void k_loss(const float* __restrict__ mpart, const float* __restrict__ lpart,
                       const float* __restrict__ lablog, const int* __restrict__ tgt_lens,
                       float* __restrict__ out){
  int tid = threadIdx.x;
  float local = 0.f;
  for (int n = tid; n < TS*32; n += 256){
    int t = n >> 5, b = n & 31;
    if (t < tgt_lens[b] - 1){
      const float* mp = mpart + (size_t)n*250;
      const float* lp = lpart + (size_t)n*250;
      float M = -1e30f;
      for (int c2=0;c2<250;c2++) M = fmaxf(M, mp[c2]);
      float L = 0.f;
      for (int c2=0;c2<250;c2++) L += lp[c2]*expf(mp[c2] - M);
      local += (M + logf(L)) - lablog[n];
    }
  }
  __shared__ float red[256];
  red[tid] = local; __syncthreads();
  for (int s2 = 128; s2 > 0; s2 >>= 1){
    if (tid < s2) red[tid] += red[tid + s2];
    __syncthreads();
  }
  if (tid == 0) out[0] = red[0];
}

extern "C" void kernel_launch(void* const* d_in, const int* in_sizes, int n_in,
                              void* d_out, int out_size, void* d_ws, size_t ws_size,
                              hipStream_t stream){
  const float* enc      = (const float*)d_in[0];
  const float* es       = (const float*)d_in[1];
  const int*   tok      = (const int*)  d_in[2];
  const int*   enc_lens = (const int*)  d_in[3];
  const int*   tgt_lens = (const int*)  d_in[4];
  const float* E        = (const float*)d_in[5];
  const float* P        = (const float*)d_in[6];
  const float* W0       = (const float*)d_in[7];
  const float* U0       = (const float*)d_in[8];
  const float* b0       = (const float*)d_in[9];
  const float* W1       = (const float*)d_in[10];
  const float* U1       = (const float*)d_in[11];
  const float* b1       = (const float*)d_in[12];
  const float* Wo       = (const float*)d_in[13];
  const float* bo       = (const float*)d_in[14];
  float* out = (float*)d_out;

  float* fb = (float*)d_ws;
  size_t fo = 0;
  float* feats = fb + fo; fo += (size_t)TS*32*2048;
  float* hp    = fb + fo; fo += (size_t)TS*32*EMB_;
  float* mpart = fb + fo; fo += (size_t)TS*32*250;
  float* lpart = fb + fo; fo += (size_t)TS*32*250;
  float* lab   = fb + fo; fo += (size_t)TS*32;
  float* c0    = fb + fo; fo += 32*H_;
  float* c1    = fb + fo; fo += 32*H_;
  unsigned* bar = (unsigned*)(fb + fo); fo += 16;
  __bf16* bb = (__bf16*)(fb + fo);
  size_t bo2 = 0;
  __bf16* WP0  = bb + bo2; bo2 += (size_t)4096*2560;
  __bf16* WP1  = bb + bo2; bo2 += (size_t)4096*2048;
  __bf16* encb = bb + bo2; bo2 += (size_t)S_*32*C_;
  __bf16* embb = bb + bo2; bo2 += (size_t)TS*32*EMB_;
  __bf16* Eb   = bb + bo2; bo2 += (size_t)VOCAB_*RANK_;
  __bf16* rbuf = bb + bo2; bo2 += (size_t)TS*32*RANK_;
  __bf16* xa0a = bb + bo2; bo2 += (size_t)32*2560;
  __bf16* xa0b = bb + bo2; bo2 += (size_t)32*2560;
  __bf16* xa1a = bb + bo2; bo2 += (size_t)32*2048;
  __bf16* xa1b = bb + bo2; bo2 += (size_t)32*2048;

  k_init<<<128, 256, 0, stream>>>(es, xa0a, xa1a, c0, c1, bar);
  k_cvt<<<(S_*32*C_/4 + 255)/256, 256, 0, stream>>>(enc, encb, S_*32*C_);
  k_cvt<<<(VOCAB_*RANK_/4 + 255)/256, 256, 0, stream>>>(E, Eb, VOCAB_*RANK_);
  k_embed<<<TS*32, 128, 0, stream>>>(E, P, tok, embb, xa0a);
  k_pack<<<dim3(80,64), 256, 0, stream>>>(W0, 1536, U0, WP0, 1280, 40);
  k_pack<<<dim3(64,64), 256, 0, stream>>>(W1, 1024, U1, WP1, 1024, 32);

  k_loop<<<NBLK, 256, 0, stream>>>(WP0, WP1, b0, b1, c0, c1,
                                   xa0a, xa0b, xa1a, xa1b,
                                   encb, enc_lens, embb, feats, bar);

  k_hproj<<<dim3(TS,4), 256, 0, stream>>>(feats, Wo, bo, hp);
  k_rproj<<<TS*32, 128, 0, stream>>>(hp, P, rbuf);
  k_vocab_mfma<<<dim3(TS,250), 256, 0, stream>>>(rbuf, Eb, tok, mpart, lpart, lab);
  k_loss<<<1, 256, 0, stream>>>(mpart, lpart, lab, tgt_lens, out);
}

// Round 4
// 3130.052 us; speedup vs baseline: 1.4182x; 1.4182x over previous
//
#include <hip/hip_runtime.h>
#include <math.h>

#define S_   56
#define B_   32
#define C_   1024
#define T_   48
#define TS   47
#define H_   1024
#define EMB_ 512
#define RANK_ 128
#define VOCAB_ 32000
#define G4   4096
#define NBLK 128

using bf16x8 = __attribute__((ext_vector_type(8))) __bf16;
using f32x4  = __attribute__((ext_vector_type(4))) float;

__device__ __forceinline__ float sigmoidf_(float x){ return 1.0f/(1.0f+expf(-x)); }
__device__ __forceinline__ float b2f(__bf16 x){ return (float)x; }

// ---------------- shared-memory union for the persistent kernel ----------------
struct GemmShared {
  __bf16 As[2][2][32][40];   // [buf][khalf][m][k(+pad)]
  float  Gp[2][32][17];
  float  Gs[32][33];
};
struct AttnShared {
  float hS[1024];
  float sS[64];
  float pS[64];
  float cred[128][8];
};
union alignas(16) SharedU { GemmShared g; AttnShared a; };

// ---------------- grid barrier (monotonic counter) ----------------
// RELEASE add (one vmcnt-drain+wbL2 per block), RELAXED polls (no cache ops),
// then ONE agent-scope acquire fence (single buffer_inv). Round-3's bug was
// ACQUIRE polling: buffer_inv per poll iteration -> L2 invalidation storm.
__device__ __forceinline__ void grid_bar(unsigned* bar, unsigned target){
  __syncthreads();
  if (threadIdx.x == 0){
    __hip_atomic_fetch_add(bar, 1u, __ATOMIC_RELEASE, __HIP_MEMORY_SCOPE_AGENT);
    while (__hip_atomic_load(bar, __ATOMIC_RELAXED, __HIP_MEMORY_SCOPE_AGENT) < target)
      __builtin_amdgcn_s_sleep(1);
    __builtin_amdgcn_fence(__ATOMIC_ACQUIRE, "agent");
  }
  __syncthreads();
}

// ---------------- init ----------------
__global__ void k_init(const float* __restrict__ es, __bf16* xa0a, __bf16* xa1a,
                       float* c0, float* c1, unsigned* bar){
  int i = blockIdx.x*blockDim.x + threadIdx.x;
  if (i < 32*H_){
    int b = i >> 10, j = i & 1023;
    xa0a[(size_t)b*2560 + 1536 + j] = (__bf16)es[i];           // h0 <- es[0]
    xa0a[(size_t)b*2560 + 512  + j] = (__bf16)0.0f;            // ctx = 0
    xa1a[(size_t)b*2048 + 1024 + j] = (__bf16)es[32*H_ + i];   // h1 <- es[1]
    c0[i] = 0.f; c1[i] = 0.f;
  }
  if (blockIdx.x == 0 && threadIdx.x == 0) bar[0] = 0u;
}

// ---------------- fp32 -> bf16 ----------------
__global__ void k_cvt(const float* __restrict__ src, __bf16* __restrict__ dst, int n){
  int i = (blockIdx.x*blockDim.x + threadIdx.x)*4;
  if (i < n){
    float4 v = *(const float4*)(src + i);
    dst[i+0]=(__bf16)v.x; dst[i+1]=(__bf16)v.y; dst[i+2]=(__bf16)v.z; dst[i+3]=(__bf16)v.w;
  }
}

// ---------------- embedding ----------------
__global__ void k_embed(const float* __restrict__ E, const float* __restrict__ P,
                        const int* __restrict__ tok, __bf16* __restrict__ embb,
                        __bf16* __restrict__ xa0a){
  int blk = blockIdx.x;            // t*32+b
  int t = blk >> 5, b = blk & 31, tid = threadIdx.x;   // 128 threads
  __shared__ float er[RANK_];
  int tk = tok[b*T_ + t];
  er[tid] = E[(size_t)tk*RANK_ + tid];
  __syncthreads();
  float4 acc = {0.f,0.f,0.f,0.f};
  int e = tid*4;
  for (int r2 = 0; r2 < RANK_; r2++){
    float ev = er[r2];
    float4 p = *(const float4*)(P + (size_t)r2*EMB_ + e);
    acc.x += ev*p.x; acc.y += ev*p.y; acc.z += ev*p.z; acc.w += ev*p.w;
  }
  size_t o = (size_t)blk*EMB_ + e;
  embb[o+0]=(__bf16)acc.x; embb[o+1]=(__bf16)acc.y;
  embb[o+2]=(__bf16)acc.z; embb[o+3]=(__bf16)acc.w;
  if (t == 0){
    size_t o2 = (size_t)b*2560 + e;
    xa0a[o2+0]=(__bf16)acc.x; xa0a[o2+1]=(__bf16)acc.y;
    xa0a[o2+2]=(__bf16)acc.z; xa0a[o2+3]=(__bf16)acc.w;
  }
}

// ---------------- pack [W;U] into MFMA B-fragment order ----------------
__global__ void k_pack(const float* __restrict__ W, int K1, const float* __restrict__ U,
                       __bf16* __restrict__ dst, int KH, int NCH){
  int kk0 = blockIdx.x*32, j0 = blockIdx.y*64, tid = threadIdx.x;
  __shared__ __bf16 Tl[32][72];
  {
    int r = tid>>3, cp = tid&7;
    int kk = kk0 + r;
    const float* src = (kk < K1) ? (W + (size_t)kk*G4 + j0 + cp*8)
                                 : (U + (size_t)(kk-K1)*G4 + j0 + cp*8);
    float4 v0 = *(const float4*)(src);
    float4 v1 = *(const float4*)(src+4);
    Tl[r][cp*8+0]=(__bf16)v0.x; Tl[r][cp*8+1]=(__bf16)v0.y;
    Tl[r][cp*8+2]=(__bf16)v0.z; Tl[r][cp*8+3]=(__bf16)v0.w;
    Tl[r][cp*8+4]=(__bf16)v1.x; Tl[r][cp*8+5]=(__bf16)v1.y;
    Tl[r][cp*8+6]=(__bf16)v1.z; Tl[r][cp*8+7]=(__bf16)v1.w;
  }
  __syncthreads();
  int jl = tid&63, q = tid>>6;
  __bf16 out8[8];
  #pragma unroll
  for (int i=0;i<8;i++) out8[i] = Tl[q*8+i][jl];
  int j = j0 + jl;
  int g = j>>10, gp = g>>1, gbit = g&1;
  int bi = (j&1023)>>3, jlo = j&7;
  int kh = kk0 / KH, ch = (kk0 % KH) >> 5;
  int lane = q*16 + gbit*8 + jlo;
  size_t off = ((((size_t)(bi*2+gp)*2 + kh)*NCH + ch)*64 + lane)*8;
  *(bf16x8*)(dst + off) = *(bf16x8*)out8;
}

// ---------------- fused gates GEMM + LSTM cell (device fn) ----------------
template<int K, int NCH>
__device__ __forceinline__ void gemm_cell(GemmShared& sgm, int bi, int tid,
    const __bf16* __restrict__ xa_in, const __bf16* __restrict__ WP,
    const float* __restrict__ bias, float* __restrict__ cst,
    __bf16* __restrict__ hout0, int stride0, int off0,
    __bf16* __restrict__ hout1, int stride1, int off1,
    float* __restrict__ houtf, int stridef, int offf)
{
  constexpr int KH = K/2;
  int w = tid>>6, lane = tid&63;
  int gp = w&1, kh = w>>1;
  f32x4 acc0 = {0,0,0,0}, acc1 = {0,0,0,0};

  int sm = (tid>>2)&31, sp = tid&3, skh = tid>>7;
  const __bf16* aptr = xa_in + (size_t)sm*K + skh*KH + sp*8;
  const __bf16* bptr = WP + ((((size_t)bi*2 + gp)*2 + kh)*NCH)*512 + lane*8;
  int am = lane&15, aq = lane>>4;

  bf16x8 sreg[4], breg[4];
  #pragma unroll
  for (int i=0;i<4;i++){
    sreg[i] = *(const bf16x8*)(aptr + (size_t)i*32);
    breg[i] = *(const bf16x8*)(bptr + (size_t)i*512);
  }

  int buf = 0;
  #pragma unroll 4
  for (int ch = 0; ch < NCH; ch++){
    int slot = ch & 3;
    *(bf16x8*)(&sgm.As[buf][skh][sm][sp*8]) = sreg[slot];
    __syncthreads();
    bf16x8 bcur = breg[slot];
    if (ch + 4 < NCH){
      sreg[slot] = *(const bf16x8*)(aptr + (size_t)(ch+4)*32);
      breg[slot] = *(const bf16x8*)(bptr + (size_t)(ch+4)*512);
    }
    bf16x8 a0 = *(const bf16x8*)(&sgm.As[buf][kh][am][aq*8]);
    bf16x8 a1 = *(const bf16x8*)(&sgm.As[buf][kh][am+16][aq*8]);
    acc0 = __builtin_amdgcn_mfma_f32_16x16x32_bf16(a0, bcur, acc0, 0, 0, 0);
    acc1 = __builtin_amdgcn_mfma_f32_16x16x32_bf16(a1, bcur, acc1, 0, 0, 0);
    buf ^= 1;
  }
  __syncthreads();
  if (kh == 1){
    #pragma unroll
    for (int rg=0; rg<4; rg++){
      sgm.Gp[gp][aq*4+rg][am]    = acc0[rg];
      sgm.Gp[gp][16+aq*4+rg][am] = acc1[rg];
    }
  }
  __syncthreads();
  if (kh == 0){
    #pragma unroll
    for (int rg=0; rg<4; rg++){
      sgm.Gs[aq*4+rg][gp*16+am]    = acc0[rg] + sgm.Gp[gp][aq*4+rg][am];
      sgm.Gs[16+aq*4+rg][gp*16+am] = acc1[rg] + sgm.Gp[gp][16+aq*4+rg][am];
    }
  }
  __syncthreads();
  int b = tid>>3, hd = tid&7;
  int j = bi*8 + hd;
  float gi = sgm.Gs[b][hd]     + bias[j];
  float gf = sgm.Gs[b][8+hd]   + bias[1024 + j];
  float gg = sgm.Gs[b][16+hd]  + bias[2048 + j];
  float go = sgm.Gs[b][24+hd]  + bias[3072 + j];
  float ii = sigmoidf_(gi), ff = sigmoidf_(gf), gv = tanhf(gg), oo = sigmoidf_(go);
  float cv = ff*cst[b*1024 + j] + ii*gv;
  float hv = oo*tanhf(cv);
  cst[b*1024 + j] = cv;
  hout0[(size_t)b*stride0 + off0 + j] = (__bf16)hv;
  if (hout1) hout1[(size_t)b*stride1 + off1 + j] = (__bf16)hv;
  if (houtf) houtf[(size_t)b*stridef + offf + j] = hv;
}

// ---------------- attention for one batch row (device fn) ----------------
__device__ __forceinline__ void attn_block(AttnShared& sa, int b, int tid,
    const __bf16* __restrict__ encb, const int* __restrict__ enc_lens,
    float* __restrict__ featst, __bf16* __restrict__ xa0q,
    const __bf16* __restrict__ embnext)
{
  #pragma unroll
  for (int i=0;i<4;i++) sa.hS[tid + i*256] = featst[(size_t)b*2048 + tid + i*256];
  __syncthreads();
  int wv = tid >> 6, lane = tid & 63;
  for (int s = wv; s < S_; s += 4){
    const __bf16* er = encb + ((size_t)s*32 + b)*C_;
    float a = 0.f;
    #pragma unroll
    for (int half = 0; half < 2; half++){
      int k = lane*8 + half*512;
      bf16x8 e8 = *(const bf16x8*)(er + k);
      #pragma unroll
      for (int u=0;u<8;u++) a += b2f(e8[u]) * sa.hS[k+u];
    }
    #pragma unroll
    for (int off=32; off>0; off>>=1) a += __shfl_down(a, off);
    if (lane == 0) sa.sS[s] = a;
  }
  __syncthreads();
  if (tid < 64){
    int len = enc_lens[b];
    float sc = (tid < len && tid < S_) ? sa.sS[tid] : -1e30f;
    float m = sc;
    #pragma unroll
    for (int off=32; off>0; off>>=1) m = fmaxf(m, __shfl_xor(m, off));
    float e = expf(sc - m);
    float ssum = e;
    #pragma unroll
    for (int off=32; off>0; off>>=1) ssum += __shfl_xor(ssum, off);
    sa.pS[tid] = e / ssum;
  }
  __syncthreads();
  int cg = tid & 127, sg2 = tid >> 7;
  float a8[8];
  #pragma unroll
  for (int i=0;i<8;i++) a8[i] = 0.f;
  for (int s = sg2; s < S_; s += 2){
    float p = sa.pS[s];
    bf16x8 e8 = *(const bf16x8*)(encb + ((size_t)s*32 + b)*C_ + cg*8);
    #pragma unroll
    for (int i=0;i<8;i++) a8[i] += p * b2f(e8[i]);
  }
  if (sg2 == 1){
    #pragma unroll
    for (int i=0;i<8;i++) sa.cred[cg][i] = a8[i];
  }
  __syncthreads();
  if (sg2 == 0){
    #pragma unroll
    for (int i=0;i<8;i++){
      float v = a8[i] + sa.cred[cg][i];
      xa0q[(size_t)b*2560 + 512 + cg*8 + i] = (__bf16)v;
      featst[(size_t)b*2048 + 1024 + cg*8 + i] = v;
    }
  }
  if (embnext && tid < 64){
    *(bf16x8*)(xa0q + (size_t)b*2560 + tid*8) =
      *(const bf16x8*)(embnext + (size_t)b*512 + tid*8);
  }
}

// ---------------- persistent decode loop ----------------
__global__ __launch_bounds__(256) void k_loop(
    const __bf16* __restrict__ WP0, const __bf16* __restrict__ WP1,
    const float* __restrict__ b0, const float* __restrict__ b1,
    float* __restrict__ c0, float* __restrict__ c1,
    __bf16* xa0a, __bf16* xa0b, __bf16* xa1a, __bf16* xa1b,
    const __bf16* __restrict__ encb, const int* __restrict__ enc_lens,
    const __bf16* __restrict__ embb, float* __restrict__ feats,
    unsigned* bar)
{
  __shared__ SharedU su;
  int bi = blockIdx.x, tid = threadIdx.x;
  unsigned bcount = 0;
  __bf16* xa0[2] = {xa0a, xa0b};
  __bf16* xa1[2] = {xa1a, xa1b};

  for (int t = 0; t < TS; t++){
    int p = t & 1, q = p ^ 1;
    gemm_cell<2560,40>(su.g, bi, tid, xa0[p], WP0, b0, c0,
                       xa1[p], 2048, 0,
                       xa0[q], 2560, 1536,
                       (float*)nullptr, 0, 0);
    grid_bar(bar, NBLK*(++bcount));
    gemm_cell<2048,32>(su.g, bi, tid, xa1[p], WP1, b1, c1,
                       xa1[q], 2048, 1024,
                       (__bf16*)nullptr, 0, 0,
                       feats + (size_t)t*32*2048, 2048, 0);
    grid_bar(bar, NBLK*(++bcount));
    if (bi < 32)
      attn_block(su.a, bi, tid, encb, enc_lens, feats + (size_t)t*32*2048,
                 xa0[q], (t+1 < TS) ? (embb + (size_t)(t+1)*32*EMB_) : (const __bf16*)nullptr);
    grid_bar(bar, NBLK*(++bcount));
  }
}

// ---------------- hproj = tanh(feats @ Wo + bo) ----------------
__global__ void k_hproj(const float* __restrict__ feats, const float* __restrict__ Wo,
                        const float* __restrict__ bo, float* __restrict__ hp){
  int nt = blockIdx.x, jt = blockIdx.y, tid = threadIdx.x;
  __shared__ float Fs[32][36];
  __shared__ float Ws[32*128];
  int jg = tid & 31, bg = tid >> 5;
  float4 acc[4];
  #pragma unroll
  for (int i=0;i<4;i++) acc[i] = make_float4(0.f,0.f,0.f,0.f);
  for (int kc = 0; kc < 2048; kc += 32){
    { int b = tid & 31, kq = tid >> 5;
      *(float4*)(&Fs[b][kq*4]) =
        *(const float4*)(feats + ((size_t)nt*32 + b)*2048 + kc + kq*4); }
    #pragma unroll
    for (int i2=0;i2<4;i2++){
      int idx = i2*256 + tid;
      int k = idx >> 5, jq = idx & 31;
      *(float4*)(&Ws[k*128 + jq*4]) =
        *(const float4*)(Wo + (size_t)(kc + k)*EMB_ + jt*128 + jq*4);
    }
    __syncthreads();
    #pragma unroll
    for (int k=0;k<32;k++){
      float4 w4 = *(const float4*)(&Ws[k*128 + jg*4]);
      #pragma unroll
      for (int i=0;i<4;i++){
        float xv = Fs[bg*4 + i][k];
        acc[i].x += xv*w4.x; acc[i].y += xv*w4.y;
        acc[i].z += xv*w4.z; acc[i].w += xv*w4.w;
      }
    }
    __syncthreads();
  }
  float4 b4 = *(const float4*)(bo + jt*128 + jg*4);
  #pragma unroll
  for (int i=0;i<4;i++){
    int b = bg*4 + i;
    float4 v;
    v.x = tanhf(acc[i].x + b4.x); v.y = tanhf(acc[i].y + b4.y);
    v.z = tanhf(acc[i].z + b4.z); v.w = tanhf(acc[i].w + b4.w);
    *(float4*)(hp + ((size_t)nt*32 + b)*EMB_ + jt*128 + jg*4) = v;
  }
}

// ---------------- r = hproj @ P^T  (bf16 out) ----------------
__global__ void k_rproj(const float* __restrict__ hp, const float* __restrict__ P,
                        __bf16* __restrict__ rb){
  int n = blockIdx.x, tid = threadIdx.x;   // 1504 x 128
  __shared__ float hS[EMB_];
  *(float4*)(hS + tid*4) = *(const float4*)(hp + (size_t)n*EMB_ + tid*4);
  __syncthreads();
  float a = 0.f;
  for (int e = 0; e < EMB_; e += 4){
    float4 p4 = *(const float4*)(P + (size_t)tid*EMB_ + e);
    a += p4.x*hS[e] + p4.y*hS[e+1] + p4.z*hS[e+2] + p4.w*hS[e+3];
  }
  rb[(size_t)n*RANK_ + tid] = (__bf16)a;
}

// ---------------- vocab GEMM (MFMA bf16) + online LSE partials ----------------
__global__ __launch_bounds__(256) void k_vocab_mfma(
    const __bf16* __restrict__ rb, const __bf16* __restrict__ Eb,
    const int* __restrict__ tok,
    float* __restrict__ mpart, float* __restrict__ lpart,
    float* __restrict__ lablog)
{
  int nt = blockIdx.x, vc = blockIdx.y, tid = threadIdx.x;
  int w = tid>>6, lane = tid&63;
  int h = w&1, vq = w>>1;
  int am = lane&15, aq = lane>>4;
  const __bf16* aptr = rb + ((size_t)(nt*32 + h*16 + am))*RANK_ + aq*8;
  int vbase = vc*128 + vq*64;
  f32x4 acc[4] = {{0,0,0,0},{0,0,0,0},{0,0,0,0},{0,0,0,0}};
  #pragma unroll
  for (int ks=0; ks<4; ks++){
    bf16x8 a = *(const bf16x8*)(aptr + ks*32);
    #pragma unroll
    for (int vt=0; vt<4; vt++){
      bf16x8 b8 = *(const bf16x8*)(Eb + ((size_t)(vbase + vt*16 + am))*RANK_ + ks*32 + aq*8);
      acc[vt] = __builtin_amdgcn_mfma_f32_16x16x32_bf16(a, b8, acc[vt], 0, 0, 0);
    }
  }
  __shared__ float redM[2][2][16], redL[2][2][16];
  #pragma unroll
  for (int rg=0; rg<4; rg++){
    int nl = h*16 + aq*4 + rg;
    int n  = nt*32 + nl;
    int lbl = tok[nl*T_ + nt + 1];   // b = nl, predicting token nt+1
    float m4 = -1e30f;
    #pragma unroll
    for (int vt=0; vt<4; vt++){
      float v = acc[vt][rg];
      if (vbase + vt*16 + am == lbl) lablog[n] = v;
      m4 = fmaxf(m4, v);
    }
    float M = m4;
    #pragma unroll
    for (int off=1; off<16; off<<=1) M = fmaxf(M, __shfl_xor(M, off));
    float l = 0.f;
    #pragma unroll
    for (int vt=0; vt<4; vt++) l += expf(acc[vt][rg] - M);
    #pragma unroll
    for (int off=1; off<16; off<<=1) l += __shfl_xor(l, off);
    if (am == 0){ redM[h][vq][aq*4+rg] = M; redL[h][vq][aq*4+rg] = l; }
  }
  __syncthreads();
  if (tid < 32){
    int hh = tid>>4, nl16 = tid&15;
    float M0 = redM[hh][0][nl16], M1 = redM[hh][1][nl16];
    float M = fmaxf(M0, M1);
    float L = redL[hh][0][nl16]*expf(M0-M) + redL[hh][1][nl16]*expf(M1-M);
    int n = nt*32 + hh*16 + nl16;
    mpart[(size_t)n*250 + vc] = M;
    lpart[(size_t)n*250 + vc] = L;
  }
}

// ---------------- final loss ----------------
__global__ void k_loss(const float* __restrict__ mpart, const float* __restrict__ lpart,
                       const float* __restrict__ lablog, const int* __restrict__ tgt_lens,
                       float* __restrict__ out){
  int tid = threadIdx.x;
  float local = 0.f;
  for (int n = tid; n < TS*32; n += 256){
    int t = n >> 5, b = n & 31;
    if (t < tgt_lens[b] - 1){
      const float* mp = mpart + (size_t)n*250;
      const float* lp = lpart + (size_t)n*250;
      float M = -1e30f;
      for (int c2=0;c2<250;c2++) M = fmaxf(M, mp[c2]);
      float L = 0.f;
      for (int c2=0;c2<250;c2++) L += lp[c2]*expf(mp[c2] - M);
      local += (M + logf(L)) - lablog[n];
    }
  }
  __shared__ float red[256];
  red[tid] = local; __syncthreads();
  for (int s2 = 128; s2 > 0; s2 >>= 1){
    if (tid < s2) red[tid] += red[tid + s2];
    __syncthreads();
  }
  if (tid == 0) out[0] = red[0];
}

extern "C" void kernel_launch(void* const* d_in, const int* in_sizes, int n_in,
                              void* d_out, int out_size, void* d_ws, size_t ws_size,
                              hipStream_t stream){
  const float* enc      = (const float*)d_in[0];
  const float* es       = (const float*)d_in[1];
  const int*   tok      = (const int*)  d_in[2];
  const int*   enc_lens = (const int*)  d_in[3];
  const int*   tgt_lens = (const int*)  d_in[4];
  const float* E        = (const float*)d_in[5];
  const float* P        = (const float*)d_in[6];
  const float* W0       = (const float*)d_in[7];
  const float* U0       = (const float*)d_in[8];
  const float* b0       = (const float*)d_in[9];
  const float* W1       = (const float*)d_in[10];
  const float* U1       = (const float*)d_in[11];
  const float* b1       = (const float*)d_in[12];
  const float* Wo       = (const float*)d_in[13];
  const float* bo       = (const float*)d_in[14];
  float* out = (float*)d_out;

  float* fb = (float*)d_ws;
  size_t fo = 0;
  float* feats = fb + fo; fo += (size_t)TS*32*2048;
  float* hp    = fb + fo; fo += (size_t)TS*32*EMB_;
  float* mpart = fb + fo; fo += (size_t)TS*32*250;
  float* lpart = fb + fo; fo += (size_t)TS*32*250;
  float* lab   = fb + fo; fo += (size_t)TS*32;
  float* c0    = fb + fo; fo += 32*H_;
  float* c1    = fb + fo; fo += 32*H_;
  unsigned* bar = (unsigned*)(fb + fo); fo += 16;
  __bf16* bb = (__bf16*)(fb + fo);
  size_t bo2 = 0;
  __bf16* WP0  = bb + bo2; bo2 += (size_t)4096*2560;
  __bf16* WP1  = bb + bo2; bo2 += (size_t)4096*2048;
  __bf16* encb = bb + bo2; bo2 += (size_t)S_*32*C_;
  __bf16* embb = bb + bo2; bo2 += (size_t)TS*32*EMB_;
  __bf16* Eb   = bb + bo2; bo2 += (size_t)VOCAB_*RANK_;
  __bf16* rbuf = bb + bo2; bo2 += (size_t)TS*32*RANK_;
  __bf16* xa0a = bb + bo2; bo2 += (size_t)32*2560;
  __bf16* xa0b = bb + bo2; bo2 += (size_t)32*2560;
  __bf16* xa1a = bb + bo2; bo2 += (size_t)32*2048;
  __bf16* xa1b = bb + bo2; bo2 += (size_t)32*2048;

  k_init<<<128, 256, 0, stream>>>(es, xa0a, xa1a, c0, c1, bar);
  k_cvt<<<(S_*32*C_/4 + 255)/256, 256, 0, stream>>>(enc, encb, S_*32*C_);
  k_cvt<<<(VOCAB_*RANK_/4 + 255)/256, 256, 0, stream>>>(E, Eb, VOCAB_*RANK_);
  k_embed<<<TS*32, 128, 0, stream>>>(E, P, tok, embb, xa0a);
  k_pack<<<dim3(80,64), 256, 0, stream>>>(W0, 1536, U0, WP0, 1280, 40);
  k_pack<<<dim3(64,64), 256, 0, stream>>>(W1, 1024, U1, WP1, 1024, 32);

  k_loop<<<NBLK, 256, 0, stream>>>(WP0, WP1, b0, b1, c0, c1,
                                   xa0a, xa0b, xa1a, xa1b,
                                   encb, enc_lens, embb, feats, bar);

  k_hproj<<<dim3(TS,4), 256, 0, stream>>>(feats, Wo, bo, hp);
  k_rproj<<<TS*32, 128, 0, stream>>>(hp, P, rbuf);
  k_vocab_mfma<<<dim3(TS,250), 256, 0, stream>>>(rbuf, Eb, tok, mpart, lpart, lab);
  k_loss<<<1, 256, 0, stream>>>(mpart, lpart, lab, tgt_lens, out);
}

// Round 5
// 2769.655 us; speedup vs baseline: 1.6027x; 1.1301x over previous
//
#include <hip/hip_runtime.h>
#include <math.h>

#define S_   56
#define B_   32
#define C_   1024
#define T_   48
#define TS   47
#define H_   1024
#define EMB_ 512
#define RANK_ 128
#define VOCAB_ 32000
#define G4   4096
#define NBLK 128

using bf16x8 = __attribute__((ext_vector_type(8))) __bf16;
using f32x4  = __attribute__((ext_vector_type(4))) float;

__device__ __forceinline__ float sigmoidf_(float x){ return 1.0f/(1.0f+expf(-x)); }
__device__ __forceinline__ float b2f(__bf16 x){ return (float)x; }

// ---------- device-coherent (sc0 sc1, MALL-visible) access helpers ----------
// Cross-block data uses these; weights/enc stay normally cached (L2-hot).
#define AG __HIP_MEMORY_SCOPE_AGENT
__device__ __forceinline__ bf16x8 ldc16(const __bf16* p){
  union { unsigned long long u[2]; bf16x8 v; } t;
  t.u[0] = __hip_atomic_load((const unsigned long long*)p,     __ATOMIC_RELAXED, AG);
  t.u[1] = __hip_atomic_load((const unsigned long long*)(p+4), __ATOMIC_RELAXED, AG);
  return t.v;
}
__device__ __forceinline__ void stc_u64(void* p, unsigned long long v){
  __hip_atomic_store((unsigned long long*)p, v, __ATOMIC_RELAXED, AG);
}
__device__ __forceinline__ void stc_bf16(__bf16* p, __bf16 v){
  union { __bf16 b; unsigned short s; } t; t.b = v;
  __hip_atomic_store((unsigned short*)p, t.s, __ATOMIC_RELAXED, AG);
}
__device__ __forceinline__ void stc_f32(float* p, float v){
  __hip_atomic_store(p, v, __ATOMIC_RELAXED, AG);
}
__device__ __forceinline__ float ldc_f32(const float* p){
  return __hip_atomic_load(p, __ATOMIC_RELAXED, AG);
}

// ---------------- shared-memory union for the persistent kernel ----------------
struct GemmShared {
  __bf16 As[2][2][32][40];   // [buf][khalf][m][k(+pad)]
  float  Gp[2][32][17];
  float  Gs[32][33];
};
struct AttnShared {
  float hS[1024];
  float sS[64];
  float pS[64];
  float cred[128][8];
};
union alignas(16) SharedU { GemmShared g; AttnShared a; };

// ---------------- grid barrier: NO bulk cache maintenance ----------------
// All cross-block data is sc0/sc1-coherent, so the barrier only needs:
// drain own stores (vmcnt), block-sync, relaxed RMW, relaxed poll.
__device__ __forceinline__ void grid_bar(unsigned* bar, unsigned target){
  asm volatile("s_waitcnt vmcnt(0)" ::: "memory");
  __syncthreads();
  if (threadIdx.x == 0){
    __hip_atomic_fetch_add(bar, 1u, __ATOMIC_RELAXED, AG);
    while (__hip_atomic_load(bar, __ATOMIC_RELAXED, AG) < target)
      __builtin_amdgcn_s_sleep(1);
  }
  __syncthreads();
}

// ---------------- init ----------------
__global__ void k_init(const float* __restrict__ es, __bf16* xa0a, __bf16* xa1a,
                       float* c0, float* c1, unsigned* bar){
  int i = blockIdx.x*blockDim.x + threadIdx.x;
  if (i < 32*H_){
    int b = i >> 10, j = i & 1023;
    xa0a[(size_t)b*2560 + 1536 + j] = (__bf16)es[i];           // h0 <- es[0]
    xa0a[(size_t)b*2560 + 512  + j] = (__bf16)0.0f;            // ctx = 0
    xa1a[(size_t)b*2048 + 1024 + j] = (__bf16)es[32*H_ + i];   // h1 <- es[1]
    c0[i] = 0.f; c1[i] = 0.f;
  }
  if (blockIdx.x == 0 && threadIdx.x == 0) bar[0] = 0u;
}

// ---------------- fp32 -> bf16 ----------------
__global__ void k_cvt(const float* __restrict__ src, __bf16* __restrict__ dst, int n){
  int i = (blockIdx.x*blockDim.x + threadIdx.x)*4;
  if (i < n){
    float4 v = *(const float4*)(src + i);
    dst[i+0]=(__bf16)v.x; dst[i+1]=(__bf16)v.y; dst[i+2]=(__bf16)v.z; dst[i+3]=(__bf16)v.w;
  }
}

// ---------------- embedding ----------------
__global__ void k_embed(const float* __restrict__ E, const float* __restrict__ P,
                        const int* __restrict__ tok, __bf16* __restrict__ embb,
                        __bf16* __restrict__ xa0a){
  int blk = blockIdx.x;            // t*32+b
  int t = blk >> 5, b = blk & 31, tid = threadIdx.x;   // 128 threads
  __shared__ float er[RANK_];
  int tk = tok[b*T_ + t];
  er[tid] = E[(size_t)tk*RANK_ + tid];
  __syncthreads();
  float4 acc = {0.f,0.f,0.f,0.f};
  int e = tid*4;
  for (int r2 = 0; r2 < RANK_; r2++){
    float ev = er[r2];
    float4 p = *(const float4*)(P + (size_t)r2*EMB_ + e);
    acc.x += ev*p.x; acc.y += ev*p.y; acc.z += ev*p.z; acc.w += ev*p.w;
  }
  size_t o = (size_t)blk*EMB_ + e;
  embb[o+0]=(__bf16)acc.x; embb[o+1]=(__bf16)acc.y;
  embb[o+2]=(__bf16)acc.z; embb[o+3]=(__bf16)acc.w;
  if (t == 0){
    size_t o2 = (size_t)b*2560 + e;
    xa0a[o2+0]=(__bf16)acc.x; xa0a[o2+1]=(__bf16)acc.y;
    xa0a[o2+2]=(__bf16)acc.z; xa0a[o2+3]=(__bf16)acc.w;
  }
}

// ---------------- pack [W;U] into MFMA B-fragment order ----------------
__global__ void k_pack(const float* __restrict__ W, int K1, const float* __restrict__ U,
                       __bf16* __restrict__ dst, int KH, int NCH){
  int kk0 = blockIdx.x*32, j0 = blockIdx.y*64, tid = threadIdx.x;
  __shared__ __bf16 Tl[32][72];
  {
    int r = tid>>3, cp = tid&7;
    int kk = kk0 + r;
    const float* src = (kk < K1) ? (W + (size_t)kk*G4 + j0 + cp*8)
                                 : (U + (size_t)(kk-K1)*G4 + j0 + cp*8);
    float4 v0 = *(const float4*)(src);
    float4 v1 = *(const float4*)(src+4);
    Tl[r][cp*8+0]=(__bf16)v0.x; Tl[r][cp*8+1]=(__bf16)v0.y;
    Tl[r][cp*8+2]=(__bf16)v0.z; Tl[r][cp*8+3]=(__bf16)v0.w;
    Tl[r][cp*8+4]=(__bf16)v1.x; Tl[r][cp*8+5]=(__bf16)v1.y;
    Tl[r][cp*8+6]=(__bf16)v1.z; Tl[r][cp*8+7]=(__bf16)v1.w;
  }
  __syncthreads();
  int jl = tid&63, q = tid>>6;
  __bf16 out8[8];
  #pragma unroll
  for (int i=0;i<8;i++) out8[i] = Tl[q*8+i][jl];
  int j = j0 + jl;
  int g = j>>10, gp = g>>1, gbit = g&1;
  int bi = (j&1023)>>3, jlo = j&7;
  int kh = kk0 / KH, ch = (kk0 % KH) >> 5;
  int lane = q*16 + gbit*8 + jlo;
  size_t off = ((((size_t)(bi*2+gp)*2 + kh)*NCH + ch)*64 + lane)*8;
  *(bf16x8*)(dst + off) = *(bf16x8*)out8;
}

// ---------------- fused gates GEMM + LSTM cell (device fn) ----------------
template<int K, int NCH>
__device__ __forceinline__ void gemm_cell(GemmShared& sgm, int bi, int tid,
    const __bf16* __restrict__ xa_in, const __bf16* __restrict__ WP,
    const float* __restrict__ bias, float* __restrict__ cst,
    __bf16* __restrict__ hout0, int stride0, int off0,
    __bf16* __restrict__ hout1, int stride1, int off1,
    float* __restrict__ houtf, int stridef, int offf)
{
  constexpr int KH = K/2;
  int w = tid>>6, lane = tid&63;
  int gp = w&1, kh = w>>1;
  f32x4 acc0 = {0,0,0,0}, acc1 = {0,0,0,0};

  int sm = (tid>>2)&31, sp = tid&3, skh = tid>>7;
  const __bf16* aptr = xa_in + (size_t)sm*K + skh*KH + sp*8;
  const __bf16* bptr = WP + ((((size_t)bi*2 + gp)*2 + kh)*NCH)*512 + lane*8;
  int am = lane&15, aq = lane>>4;

  bf16x8 sreg[4], breg[4];
  #pragma unroll
  for (int i=0;i<4;i++){
    sreg[i] = ldc16(aptr + (size_t)i*32);                     // coherent A
    breg[i] = *(const bf16x8*)(bptr + (size_t)i*512);         // cached weights
  }

  int buf = 0;
  #pragma unroll 4
  for (int ch = 0; ch < NCH; ch++){
    int slot = ch & 3;
    *(bf16x8*)(&sgm.As[buf][skh][sm][sp*8]) = sreg[slot];
    __syncthreads();
    bf16x8 bcur = breg[slot];
    if (ch + 4 < NCH){
      sreg[slot] = ldc16(aptr + (size_t)(ch+4)*32);
      breg[slot] = *(const bf16x8*)(bptr + (size_t)(ch+4)*512);
    }
    bf16x8 a0 = *(const bf16x8*)(&sgm.As[buf][kh][am][aq*8]);
    bf16x8 a1 = *(const bf16x8*)(&sgm.As[buf][kh][am+16][aq*8]);
    acc0 = __builtin_amdgcn_mfma_f32_16x16x32_bf16(a0, bcur, acc0, 0, 0, 0);
    acc1 = __builtin_amdgcn_mfma_f32_16x16x32_bf16(a1, bcur, acc1, 0, 0, 0);
    buf ^= 1;
  }
  __syncthreads();
  if (kh == 1){
    #pragma unroll
    for (int rg=0; rg<4; rg++){
      sgm.Gp[gp][aq*4+rg][am]    = acc0[rg];
      sgm.Gp[gp][16+aq*4+rg][am] = acc1[rg];
    }
  }
  __syncthreads();
  if (kh == 0){
    #pragma unroll
    for (int rg=0; rg<4; rg++){
      sgm.Gs[aq*4+rg][gp*16+am]    = acc0[rg] + sgm.Gp[gp][aq*4+rg][am];
      sgm.Gs[16+aq*4+rg][gp*16+am] = acc1[rg] + sgm.Gp[gp][16+aq*4+rg][am];
    }
  }
  __syncthreads();
  int b = tid>>3, hd = tid&7;
  int j = bi*8 + hd;
  float gi = sgm.Gs[b][hd]     + bias[j];
  float gf = sgm.Gs[b][8+hd]   + bias[1024 + j];
  float gg = sgm.Gs[b][16+hd]  + bias[2048 + j];
  float go = sgm.Gs[b][24+hd]  + bias[3072 + j];
  float ii = sigmoidf_(gi), ff = sigmoidf_(gf), gv = tanhf(gg), oo = sigmoidf_(go);
  float cv = ff*cst[b*1024 + j] + ii*gv;
  float hv = oo*tanhf(cv);
  cst[b*1024 + j] = cv;                                   // block-private, cached
  stc_bf16(hout0 + (size_t)b*stride0 + off0 + j, (__bf16)hv);
  if (hout1) stc_bf16(hout1 + (size_t)b*stride1 + off1 + j, (__bf16)hv);
  if (houtf) stc_f32(houtf + (size_t)b*stridef + offf + j, hv);
}

// ---------------- attention for one batch row (device fn) ----------------
__device__ __forceinline__ void attn_block(AttnShared& sa, int b, int tid,
    const __bf16* __restrict__ encb, const int* __restrict__ enc_lens,
    float* __restrict__ featst, __bf16* __restrict__ xa0q,
    const __bf16* __restrict__ embnext)
{
  #pragma unroll
  for (int i=0;i<4;i++) sa.hS[tid + i*256] = ldc_f32(featst + (size_t)b*2048 + tid + i*256);
  __syncthreads();
  int wv = tid >> 6, lane = tid & 63;
  for (int s = wv; s < S_; s += 4){
    const __bf16* er = encb + ((size_t)s*32 + b)*C_;
    float a = 0.f;
    #pragma unroll
    for (int half = 0; half < 2; half++){
      int k = lane*8 + half*512;
      bf16x8 e8 = *(const bf16x8*)(er + k);
      #pragma unroll
      for (int u=0;u<8;u++) a += b2f(e8[u]) * sa.hS[k+u];
    }
    #pragma unroll
    for (int off=32; off>0; off>>=1) a += __shfl_down(a, off);
    if (lane == 0) sa.sS[s] = a;
  }
  __syncthreads();
  if (tid < 64){
    int len = enc_lens[b];
    float sc = (tid < len && tid < S_) ? sa.sS[tid] : -1e30f;
    float m = sc;
    #pragma unroll
    for (int off=32; off>0; off>>=1) m = fmaxf(m, __shfl_xor(m, off));
    float e = expf(sc - m);
    float ssum = e;
    #pragma unroll
    for (int off=32; off>0; off>>=1) ssum += __shfl_xor(ssum, off);
    sa.pS[tid] = e / ssum;
  }
  __syncthreads();
  int cg = tid & 127, sg2 = tid >> 7;
  float a8[8];
  #pragma unroll
  for (int i=0;i<8;i++) a8[i] = 0.f;
  for (int s = sg2; s < S_; s += 2){
    float p = sa.pS[s];
    bf16x8 e8 = *(const bf16x8*)(encb + ((size_t)s*32 + b)*C_ + cg*8);
    #pragma unroll
    for (int i=0;i<8;i++) a8[i] += p * b2f(e8[i]);
  }
  if (sg2 == 1){
    #pragma unroll
    for (int i=0;i<8;i++) sa.cred[cg][i] = a8[i];
  }
  __syncthreads();
  if (sg2 == 0){
    union { __bf16 bb[8]; unsigned long long u[2]; } cu;
    #pragma unroll
    for (int i=0;i<8;i++){
      float v = a8[i] + sa.cred[cg][i];
      cu.bb[i] = (__bf16)v;
      featst[(size_t)b*2048 + 1024 + cg*8 + i] = v;   // consumed post-kernel only
    }
    stc_u64(xa0q + (size_t)b*2560 + 512 + cg*8,     cu.u[0]);
    stc_u64(xa0q + (size_t)b*2560 + 512 + cg*8 + 4, cu.u[1]);
  }
  if (embnext && tid < 64){
    union { bf16x8 v; unsigned long long u[2]; } t;
    t.v = *(const bf16x8*)(embnext + (size_t)b*512 + tid*8);
    stc_u64(xa0q + (size_t)b*2560 + tid*8,     t.u[0]);
    stc_u64(xa0q + (size_t)b*2560 + tid*8 + 4, t.u[1]);
  }
}

// ---------------- persistent decode loop ----------------
__global__ __launch_bounds__(256) void k_loop(
    const __bf16* __restrict__ WP0, const __bf16* __restrict__ WP1,
    const float* __restrict__ b0, const float* __restrict__ b1,
    float* __restrict__ c0, float* __restrict__ c1,
    __bf16* xa0a, __bf16* xa0b, __bf16* xa1a, __bf16* xa1b,
    const __bf16* __restrict__ encb, const int* __restrict__ enc_lens,
    const __bf16* __restrict__ embb, float* __restrict__ feats,
    unsigned* bar)
{
  __shared__ SharedU su;
  int bi = blockIdx.x, tid = threadIdx.x;
  unsigned bcount = 0;
  __bf16* xa0[2] = {xa0a, xa0b};
  __bf16* xa1[2] = {xa1a, xa1b};

  for (int t = 0; t < TS; t++){
    int p = t & 1, q = p ^ 1;
    gemm_cell<2560,40>(su.g, bi, tid, xa0[p], WP0, b0, c0,
                       xa1[p], 2048, 0,
                       xa0[q], 2560, 1536,
                       (float*)nullptr, 0, 0);
    grid_bar(bar, NBLK*(++bcount));
    gemm_cell<2048,32>(su.g, bi, tid, xa1[p], WP1, b1, c1,
                       xa1[q], 2048, 1024,
                       (__bf16*)nullptr, 0, 0,
                       feats + (size_t)t*32*2048, 2048, 0);
    grid_bar(bar, NBLK*(++bcount));
    if (bi < 32)
      attn_block(su.a, bi, tid, encb, enc_lens, feats + (size_t)t*32*2048,
                 xa0[q], (t+1 < TS) ? (embb + (size_t)(t+1)*32*EMB_) : (const __bf16*)nullptr);
    grid_bar(bar, NBLK*(++bcount));
  }
}

// ---------------- hproj = tanh(feats @ Wo + bo) ----------------
__global__ void k_hproj(const float* __restrict__ feats, const float* __restrict__ Wo,
                        const float* __restrict__ bo, float* __restrict__ hp){
  int nt = blockIdx.x, jt = blockIdx.y, tid = threadIdx.x;
  __shared__ float Fs[32][36];
  __shared__ float Ws[32*128];
  int jg = tid & 31, bg = tid >> 5;
  float4 acc[4];
  #pragma unroll
  for (int i=0;i<4;i++) acc[i] = make_float4(0.f,0.f,0.f,0.f);
  for (int kc = 0; kc < 2048; kc += 32){
    { int b = tid & 31, kq = tid >> 5;
      *(float4*)(&Fs[b][kq*4]) =
        *(const float4*)(feats + ((size_t)nt*32 + b)*2048 + kc + kq*4); }
    #pragma unroll
    for (int i2=0;i2<4;i2++){
      int idx = i2*256 + tid;
      int k = idx >> 5, jq = idx & 31;
      *(float4*)(&Ws[k*128 + jq*4]) =
        *(const float4*)(Wo + (size_t)(kc + k)*EMB_ + jt*128 + jq*4);
    }
    __syncthreads();
    #pragma unroll
    for (int k=0;k<32;k++){
      float4 w4 = *(const float4*)(&Ws[k*128 + jg*4]);
      #pragma unroll
      for (int i=0;i<4;i++){
        float xv = Fs[bg*4 + i][k];
        acc[i].x += xv*w4.x; acc[i].y += xv*w4.y;
        acc[i].z += xv*w4.z; acc[i].w += xv*w4.w;
      }
    }
    __syncthreads();
  }
  float4 b4 = *(const float4*)(bo + jt*128 + jg*4);
  #pragma unroll
  for (int i=0;i<4;i++){
    int b = bg*4 + i;
    float4 v;
    v.x = tanhf(acc[i].x + b4.x); v.y = tanhf(acc[i].y + b4.y);
    v.z = tanhf(acc[i].z + b4.z); v.w = tanhf(acc[i].w + b4.w);
    *(float4*)(hp + ((size_t)nt*32 + b)*EMB_ + jt*128 + jg*4) = v;
  }
}

// ---------------- r = hproj @ P^T  (bf16 out) ----------------
__global__ void k_rproj(const float* __restrict__ hp, const float* __restrict__ P,
                        __bf16* __restrict__ rb){
  int n = blockIdx.x, tid = threadIdx.x;   // 1504 x 128
  __shared__ float hS[EMB_];
  *(float4*)(hS + tid*4) = *(const float4*)(hp + (size_t)n*EMB_ + tid*4);
  __syncthreads();
  float a = 0.f;
  for (int e = 0; e < EMB_; e += 4){
    float4 p4 = *(const float4*)(P + (size_t)tid*EMB_ + e);
    a += p4.x*hS[e] + p4.y*hS[e+1] + p4.z*hS[e+2] + p4.w*hS[e+3];
  }
  rb[(size_t)n*RANK_ + tid] = (__bf16)a;
}

// ---------------- vocab GEMM: grid 250 v-chunks, loop all 47 n-tiles ----------------
// E-fragments register-resident (read once), r-tiles L2-hot. mpart/lpart [n][250].
__global__ __launch_bounds__(256) void k_vocab2(
    const __bf16* __restrict__ rb, const __bf16* __restrict__ Eb,
    const int* __restrict__ tok,
    float* __restrict__ mpart, float* __restrict__ lpart,
    float* __restrict__ lablog)
{
  int vc = blockIdx.x, tid = threadIdx.x;
  int w = tid>>6, lane = tid&63;
  int am = lane&15, aq = lane>>4;
  int vb = vc*128 + w*32;                 // this wave's v-base (32 vocab cols)
  bf16x8 bfr[2][4];
  #pragma unroll
  for (int vt=0; vt<2; vt++)
    #pragma unroll
    for (int ks=0; ks<4; ks++)
      bfr[vt][ks] = *(const bf16x8*)(Eb + ((size_t)(vb + vt*16 + am))*RANK_ + ks*32 + aq*8);

  __shared__ float redM[4][32], redL[4][32];
  for (int nt = 0; nt < TS; nt++){
    f32x4 acc[2][2] = {{{0,0,0,0},{0,0,0,0}},{{0,0,0,0},{0,0,0,0}}};
    #pragma unroll
    for (int mt=0; mt<2; mt++){
      #pragma unroll
      for (int ks=0; ks<4; ks++){
        bf16x8 a = *(const bf16x8*)(rb + ((size_t)(nt*32 + mt*16 + am))*RANK_ + ks*32 + aq*8);
        acc[mt][0] = __builtin_amdgcn_mfma_f32_16x16x32_bf16(a, bfr[0][ks], acc[mt][0], 0,0,0);
        acc[mt][1] = __builtin_amdgcn_mfma_f32_16x16x32_bf16(a, bfr[1][ks], acc[mt][1], 0,0,0);
      }
    }
    #pragma unroll
    for (int mt=0; mt<2; mt++){
      #pragma unroll
      for (int rg=0; rg<4; rg++){
        int row = mt*16 + aq*4 + rg;         // = batch b
        int n = nt*32 + row;
        int lbl = tok[row*T_ + nt + 1];
        float v0 = acc[mt][0][rg], v1 = acc[mt][1][rg];
        if (vb + am == lbl)      lablog[n] = v0;
        if (vb + 16 + am == lbl) lablog[n] = v1;
        float m = fmaxf(v0, v1);
        #pragma unroll
        for (int off=1; off<16; off<<=1) m = fmaxf(m, __shfl_xor(m, off));
        float l = expf(v0 - m) + expf(v1 - m);
        #pragma unroll
        for (int off=1; off<16; off<<=1) l += __shfl_xor(l, off);
        if (am == 0){ redM[w][row] = m; redL[w][row] = l; }
      }
    }
    __syncthreads();
    if (tid < 32){
      float M = fmaxf(fmaxf(redM[0][tid], redM[1][tid]), fmaxf(redM[2][tid], redM[3][tid]));
      float L = 0.f;
      #pragma unroll
      for (int ww=0; ww<4; ww++) L += redL[ww][tid]*expf(redM[ww][tid] - M);
      mpart[(size_t)(nt*32 + tid)*250 + vc] = M;
      lpart[(size_t)(nt*32 + tid)*250 + vc] = L;
    }
    __syncthreads();
  }
}

// ---------------- loss stage 1: per-t partial (47 blocks) ----------------
__global__ void k_loss1(const float* __restrict__ mpart, const float* __restrict__ lpart,
                        const float* __restrict__ lablog, const int* __restrict__ tgt_lens,
                        float* __restrict__ tpart){
  int t = blockIdx.x, tid = threadIdx.x;   // 256 threads: 8 per batch row
  int row = tid >> 3, cq = tid & 7;
  int n = t*32 + row;
  float m = -1e30f;
  for (int c = cq; c < 250; c += 8) m = fmaxf(m, mpart[(size_t)n*250 + c]);
  #pragma unroll
  for (int off=1; off<8; off<<=1) m = fmaxf(m, __shfl_xor(m, off));
  float l = 0.f;
  for (int c = cq; c < 250; c += 8) l += lpart[(size_t)n*250 + c]*expf(mpart[(size_t)n*250 + c] - m);
  #pragma unroll
  for (int off=1; off<8; off<<=1) l += __shfl_xor(l, off);
  __shared__ float red[32];
  if (cq == 0)
    red[row] = (t < tgt_lens[row] - 1) ? (m + logf(l) - lablog[n]) : 0.f;
  __syncthreads();
  if (tid == 0){
    float s = 0.f;
    #pragma unroll
    for (int i=0;i<32;i++) s += red[i];
    tpart[t] = s;
  }
}

// ---------------- loss stage 2: deterministic final sum ----------------
__global__ void k_loss2(const float* __restrict__ tpart, float* __restrict__ out){
  int tid = threadIdx.x;   // 64
  float v = (tid < TS) ? tpart[tid] : 0.f;
  #pragma unroll
  for (int off=32; off>0; off>>=1) v += __shfl_down(v, off);
  if (tid == 0) out[0] = v;
}

extern "C" void kernel_launch(void* const* d_in, const int* in_sizes, int n_in,
                              void* d_out, int out_size, void* d_ws, size_t ws_size,
                              hipStream_t stream){
  const float* enc      = (const float*)d_in[0];
  const float* es       = (const float*)d_in[1];
  const int*   tok      = (const int*)  d_in[2];
  const int*   enc_lens = (const int*)  d_in[3];
  const int*   tgt_lens = (const int*)  d_in[4];
  const float* E        = (const float*)d_in[5];
  const float* P        = (const float*)d_in[6];
  const float* W0       = (const float*)d_in[7];
  const float* U0       = (const float*)d_in[8];
  const float* b0       = (const float*)d_in[9];
  const float* W1       = (const float*)d_in[10];
  const float* U1       = (const float*)d_in[11];
  const float* b1       = (const float*)d_in[12];
  const float* Wo       = (const float*)d_in[13];
  const float* bo       = (const float*)d_in[14];
  float* out = (float*)d_out;

  float* fb = (float*)d_ws;
  size_t fo = 0;
  float* feats = fb + fo; fo += (size_t)TS*32*2048;
  float* hp    = fb + fo; fo += (size_t)TS*32*EMB_;
  float* mpart = fb + fo; fo += (size_t)TS*32*250;
  float* lpart = fb + fo; fo += (size_t)TS*32*250;
  float* lab   = fb + fo; fo += (size_t)TS*32;
  float* tpart = fb + fo; fo += 64;
  float* c0    = fb + fo; fo += 32*H_;
  float* c1    = fb + fo; fo += 32*H_;
  unsigned* bar = (unsigned*)(fb + fo); fo += 16;
  __bf16* bb = (__bf16*)(fb + fo);
  size_t bo2 = 0;
  __bf16* WP0  = bb + bo2; bo2 += (size_t)4096*2560;
  __bf16* WP1  = bb + bo2; bo2 += (size_t)4096*2048;
  __bf16* encb = bb + bo2; bo2 += (size_t)S_*32*C_;
  __bf16* embb = bb + bo2; bo2 += (size_t)TS*32*EMB_;
  __bf16* Eb   = bb + bo2; bo2 += (size_t)VOCAB_*RANK_;
  __bf16* rbuf = bb + bo2; bo2 += (size_t)TS*32*RANK_;
  __bf16* xa0a = bb + bo2; bo2 += (size_t)32*2560;
  __bf16* xa0b = bb + bo2; bo2 += (size_t)32*2560;
  __bf16* xa1a = bb + bo2; bo2 += (size_t)32*2048;
  __bf16* xa1b = bb + bo2; bo2 += (size_t)32*2048;

  k_init<<<128, 256, 0, stream>>>(es, xa0a, xa1a, c0, c1, bar);
  k_cvt<<<(S_*32*C_/4 + 255)/256, 256, 0, stream>>>(enc, encb, S_*32*C_);
  k_cvt<<<(VOCAB_*RANK_/4 + 255)/256, 256, 0, stream>>>(E, Eb, VOCAB_*RANK_);
  k_embed<<<TS*32, 128, 0, stream>>>(E, P, tok, embb, xa0a);
  k_pack<<<dim3(80,64), 256, 0, stream>>>(W0, 1536, U0, WP0, 1280, 40);
  k_pack<<<dim3(64,64), 256, 0, stream>>>(W1, 1024, U1, WP1, 1024, 32);

  k_loop<<<NBLK, 256, 0, stream>>>(WP0, WP1, b0, b1, c0, c1,
                                   xa0a, xa0b, xa1a, xa1b,
                                   encb, enc_lens, embb, feats, bar);

  k_hproj<<<dim3(TS,4), 256, 0, stream>>>(feats, Wo, bo, hp);
  k_rproj<<<TS*32, 128, 0, stream>>>(hp, P, rbuf);
  k_vocab2<<<250, 256, 0, stream>>>(rbuf, Eb, tok, mpart, lpart, lab);
  k_loss1<<<TS, 256, 0, stream>>>(mpart, lpart, lab, tgt_lens, tpart);
  k_loss2<<<1, 64, 0, stream>>>(tpart, out);
}

// Round 6
// 2031.890 us; speedup vs baseline: 2.1846x; 1.3631x over previous
//
#include <hip/hip_runtime.h>
#include <math.h>

#define S_   56
#define B_   32
#define C_   1024
#define T_   48
#define TS   47
#define H_   1024
#define EMB_ 512
#define RANK_ 128
#define VOCAB_ 32000
#define G4   4096
#define NBLK 128

using bf16x8 = __attribute__((ext_vector_type(8))) __bf16;
using f32x4  = __attribute__((ext_vector_type(4))) float;

__device__ __forceinline__ float sigmoidf_(float x){ return 1.0f/(1.0f+expf(-x)); }
__device__ __forceinline__ float b2f(__bf16 x){ return (float)x; }

// ---------- device-coherent (MALL-visible) access helpers ----------
#define AG __HIP_MEMORY_SCOPE_AGENT
__device__ __forceinline__ bf16x8 ldc16(const __bf16* p){
  union { unsigned long long u[2]; bf16x8 v; } t;
  t.u[0] = __hip_atomic_load((const unsigned long long*)p,     __ATOMIC_RELAXED, AG);
  t.u[1] = __hip_atomic_load((const unsigned long long*)(p+4), __ATOMIC_RELAXED, AG);
  return t.v;
}
__device__ __forceinline__ void stc_u64(void* p, unsigned long long v){
  __hip_atomic_store((unsigned long long*)p, v, __ATOMIC_RELAXED, AG);
}
__device__ __forceinline__ void stc_bf16(__bf16* p, __bf16 v){
  union { __bf16 b; unsigned short s; } t; t.b = v;
  __hip_atomic_store((unsigned short*)p, t.s, __ATOMIC_RELAXED, AG);
}

// ---------------- shared-memory union for the persistent kernel ----------------
struct GemmShared {
  __bf16 As[2][4][32][40];   // [buf][kq][m][k(+pad)]
  float  Gp[2][3][32][17];   // partials from kq=1..3
  float  Gs[32][33];
};
struct AttnShared {
  float hS[1024];
  float sS[64];
  float pS[64];
  float cred[3][128][8];
};
union alignas(16) SharedU { GemmShared g; AttnShared a; };

// ---------------- hierarchical grid barrier (monotonic, relaxed) ----------------
// 8 group counters (128B apart) x 16 arrivals each -> 1 master bump per group.
__device__ __forceinline__ void grid_bar(unsigned* bars, int bi, unsigned e){
  asm volatile("s_waitcnt vmcnt(0)" ::: "memory");
  __syncthreads();
  if (threadIdx.x == 0){
    unsigned* grp = bars + 32*(1 + (bi & 7));
    unsigned old = __hip_atomic_fetch_add(grp, 1u, __ATOMIC_RELAXED, AG);
    if (old == 16u*e - 1u)
      __hip_atomic_fetch_add(bars, 1u, __ATOMIC_RELAXED, AG);
    while (__hip_atomic_load(bars, __ATOMIC_RELAXED, AG) < 8u*e)
      __builtin_amdgcn_s_sleep(1);
  }
  __syncthreads();
}

// ---------------- init ----------------
__global__ void k_init(const float* __restrict__ es, __bf16* xa0a, __bf16* xa1a,
                       float* c0, float* c1, unsigned* bars){
  int i = blockIdx.x*blockDim.x + threadIdx.x;
  if (i < 32*H_){
    int b = i >> 10, j = i & 1023;
    xa0a[(size_t)b*2560 + 1536 + j] = (__bf16)es[i];           // h0 <- es[0]
    xa0a[(size_t)b*2560 + 512  + j] = (__bf16)0.0f;            // ctx = 0
    xa1a[(size_t)b*2048 + 1024 + j] = (__bf16)es[32*H_ + i];   // h1 <- es[1]
    c0[i] = 0.f; c1[i] = 0.f;
  }
  if (i < 512) bars[i] = 0u;
}

// ---------------- fp32 -> bf16 ----------------
__global__ void k_cvt(const float* __restrict__ src, __bf16* __restrict__ dst, int n){
  int i = (blockIdx.x*blockDim.x + threadIdx.x)*4;
  if (i < n){
    float4 v = *(const float4*)(src + i);
    dst[i+0]=(__bf16)v.x; dst[i+1]=(__bf16)v.y; dst[i+2]=(__bf16)v.z; dst[i+3]=(__bf16)v.w;
  }
}

// ---------------- embedding ----------------
__global__ void k_embed(const float* __restrict__ E, const float* __restrict__ P,
                        const int* __restrict__ tok, __bf16* __restrict__ embb,
                        __bf16* __restrict__ xa0a){
  int blk = blockIdx.x;            // t*32+b
  int t = blk >> 5, b = blk & 31, tid = threadIdx.x;   // 128 threads
  __shared__ float er[RANK_];
  int tk = tok[b*T_ + t];
  er[tid] = E[(size_t)tk*RANK_ + tid];
  __syncthreads();
  float4 acc = {0.f,0.f,0.f,0.f};
  int e = tid*4;
  for (int r2 = 0; r2 < RANK_; r2++){
    float ev = er[r2];
    float4 p = *(const float4*)(P + (size_t)r2*EMB_ + e);
    acc.x += ev*p.x; acc.y += ev*p.y; acc.z += ev*p.z; acc.w += ev*p.w;
  }
  size_t o = (size_t)blk*EMB_ + e;
  embb[o+0]=(__bf16)acc.x; embb[o+1]=(__bf16)acc.y;
  embb[o+2]=(__bf16)acc.z; embb[o+3]=(__bf16)acc.w;
  if (t == 0){
    size_t o2 = (size_t)b*2560 + e;
    xa0a[o2+0]=(__bf16)acc.x; xa0a[o2+1]=(__bf16)acc.y;
    xa0a[o2+2]=(__bf16)acc.z; xa0a[o2+3]=(__bf16)acc.w;
  }
}

// ---------------- pack [W;U] into MFMA B-fragment order (4 k-quarters) ----------------
__global__ void k_pack(const float* __restrict__ W, int K1, const float* __restrict__ U,
                       __bf16* __restrict__ dst, int K, int NCHQ){
  int kk0 = blockIdx.x*32, j0 = blockIdx.y*64, tid = threadIdx.x;
  __shared__ __bf16 Tl[32][72];
  {
    int r = tid>>3, cp = tid&7;
    int kk = kk0 + r;
    const float* src = (kk < K1) ? (W + (size_t)kk*G4 + j0 + cp*8)
                                 : (U + (size_t)(kk-K1)*G4 + j0 + cp*8);
    float4 v0 = *(const float4*)(src);
    float4 v1 = *(const float4*)(src+4);
    Tl[r][cp*8+0]=(__bf16)v0.x; Tl[r][cp*8+1]=(__bf16)v0.y;
    Tl[r][cp*8+2]=(__bf16)v0.z; Tl[r][cp*8+3]=(__bf16)v0.w;
    Tl[r][cp*8+4]=(__bf16)v1.x; Tl[r][cp*8+5]=(__bf16)v1.y;
    Tl[r][cp*8+6]=(__bf16)v1.z; Tl[r][cp*8+7]=(__bf16)v1.w;
  }
  __syncthreads();
  int jl = tid&63, q = tid>>6;
  __bf16 out8[8];
  #pragma unroll
  for (int i=0;i<8;i++) out8[i] = Tl[q*8+i][jl];
  int j = j0 + jl;
  int g = j>>10, gp = g>>1, gbit = g&1;
  int bi = (j&1023)>>3, jlo = j&7;
  int KQ = K/4;
  int kq = kk0 / KQ, ch = (kk0 % KQ) >> 5;
  int lane = q*16 + gbit*8 + jlo;
  size_t off = ((((size_t)(bi*2+gp)*4 + kq)*NCHQ + ch)*64 + lane)*8;
  *(bf16x8*)(dst + off) = *(bf16x8*)out8;
}

// ---------------- generic B-frag pack (16x16x32) for Wo / P^T ----------------
__global__ void k_packB(const float* __restrict__ src, __bf16* __restrict__ dst,
                        int K, int N, int tr){
  int kk0 = blockIdx.x*32, j0 = blockIdx.y*16, lane = threadIdx.x;  // 64 threads
  int am = lane&15, aq = lane>>4;
  int j = j0 + am;
  __bf16 o8[8];
  #pragma unroll
  for (int i=0;i<8;i++){
    int k = kk0 + aq*8 + i;
    float v = tr ? src[(size_t)j*K + k] : src[(size_t)k*N + j];
    o8[i] = (__bf16)v;
  }
  int NCH = K/32, jt = j0>>4, ch = kk0>>5;
  *(bf16x8*)(dst + (((size_t)jt*NCH + ch)*64 + lane)*8) = *(bf16x8*)o8;
}

// ---------------- fused gates GEMM + LSTM cell (512 thr, k-split 4) ----------------
template<int K, int NCHQ>
__device__ __forceinline__ void gemm_cell(GemmShared& sgm, int bi, int tid,
    const __bf16* __restrict__ xa_in, const __bf16* __restrict__ WP,
    const float* __restrict__ bias, float* __restrict__ cst,
    __bf16* __restrict__ hout0, int stride0, int off0,
    __bf16* __restrict__ hout1, int stride1, int off1,
    __bf16* __restrict__ houtf, int stridef, int offf)
{
  constexpr int KQ = K/4;
  int w = tid>>6, lane = tid&63;
  int gp = w&1, kq = w>>1;                  // gate-pair, k-quarter
  int am = lane&15, aq = lane>>4;
  f32x4 acc0 = {0,0,0,0}, acc1 = {0,0,0,0};

  int skq = tid>>7, sm = (tid>>2)&31, sp = tid&3;
  const __bf16* aptr = xa_in + (size_t)sm*K + skq*KQ + sp*8;
  const __bf16* bptr = WP + ((((size_t)bi*2 + gp)*4 + kq)*NCHQ)*512 + lane*8;

  bf16x8 sreg[4], breg[4];
  #pragma unroll
  for (int i=0;i<4;i++){
    sreg[i] = ldc16(aptr + (size_t)i*32);
    breg[i] = *(const bf16x8*)(bptr + (size_t)i*512);
  }

  int buf = 0;
  #pragma unroll 4
  for (int ch = 0; ch < NCHQ; ch++){
    int slot = ch & 3;
    *(bf16x8*)(&sgm.As[buf][skq][sm][sp*8]) = sreg[slot];
    __syncthreads();
    bf16x8 bcur = breg[slot];
    if (ch + 4 < NCHQ){
      sreg[slot] = ldc16(aptr + (size_t)(ch+4)*32);
      breg[slot] = *(const bf16x8*)(bptr + (size_t)(ch+4)*512);
    }
    bf16x8 a0 = *(const bf16x8*)(&sgm.As[buf][kq][am][aq*8]);
    bf16x8 a1 = *(const bf16x8*)(&sgm.As[buf][kq][am+16][aq*8]);
    acc0 = __builtin_amdgcn_mfma_f32_16x16x32_bf16(a0, bcur, acc0, 0, 0, 0);
    acc1 = __builtin_amdgcn_mfma_f32_16x16x32_bf16(a1, bcur, acc1, 0, 0, 0);
    buf ^= 1;
  }
  __syncthreads();
  if (kq > 0){
    #pragma unroll
    for (int rg=0; rg<4; rg++){
      sgm.Gp[gp][kq-1][aq*4+rg][am]    = acc0[rg];
      sgm.Gp[gp][kq-1][16+aq*4+rg][am] = acc1[rg];
    }
  }
  __syncthreads();
  if (kq == 0){
    #pragma unroll
    for (int rg=0; rg<4; rg++){
      int r0 = aq*4+rg, r1 = 16+aq*4+rg;
      sgm.Gs[r0][gp*16+am] = acc0[rg] + sgm.Gp[gp][0][r0][am]
                           + sgm.Gp[gp][1][r0][am] + sgm.Gp[gp][2][r0][am];
      sgm.Gs[r1][gp*16+am] = acc1[rg] + sgm.Gp[gp][0][r1][am]
                           + sgm.Gp[gp][1][r1][am] + sgm.Gp[gp][2][r1][am];
    }
  }
  __syncthreads();
  if (tid < 256){
    int b = tid>>3, hd = tid&7;
    int j = bi*8 + hd;
    float gi = sgm.Gs[b][hd]     + bias[j];
    float gf = sgm.Gs[b][8+hd]   + bias[1024 + j];
    float gg = sgm.Gs[b][16+hd]  + bias[2048 + j];
    float go = sgm.Gs[b][24+hd]  + bias[3072 + j];
    float ii = sigmoidf_(gi), ff = sigmoidf_(gf), gv = tanhf(gg), oo = sigmoidf_(go);
    float cv = ff*cst[b*1024 + j] + ii*gv;
    float hv = oo*tanhf(cv);
    cst[b*1024 + j] = cv;
    stc_bf16(hout0 + (size_t)b*stride0 + off0 + j, (__bf16)hv);
    if (hout1) stc_bf16(hout1 + (size_t)b*stride1 + off1 + j, (__bf16)hv);
    if (houtf) stc_bf16(houtf + (size_t)b*stridef + offf + j, (__bf16)hv);
  }
}

// ---------------- attention for one batch row (512 threads) ----------------
__device__ __forceinline__ void attn_block(AttnShared& sa, int b, int tid,
    const __bf16* __restrict__ encb, const int* __restrict__ enc_lens,
    __bf16* __restrict__ fbt, __bf16* __restrict__ xa0q,
    const __bf16* __restrict__ embnext)
{
  if (tid < 128){
    bf16x8 h8 = ldc16(fbt + (size_t)b*2048 + tid*8);
    #pragma unroll
    for (int u=0;u<8;u++) sa.hS[tid*8+u] = b2f(h8[u]);
  }
  __syncthreads();
  int w = tid >> 6, lane = tid & 63;
  for (int s = w; s < S_; s += 8){
    const __bf16* er = encb + ((size_t)s*32 + b)*C_;
    float a = 0.f;
    #pragma unroll
    for (int half = 0; half < 2; half++){
      int k = lane*8 + half*512;
      bf16x8 e8 = *(const bf16x8*)(er + k);
      #pragma unroll
      for (int u=0;u<8;u++) a += b2f(e8[u]) * sa.hS[k+u];
    }
    #pragma unroll
    for (int off=32; off>0; off>>=1) a += __shfl_down(a, off);
    if (lane == 0) sa.sS[s] = a;
  }
  __syncthreads();
  if (tid < 64){
    int len = enc_lens[b];
    float sc = (tid < len && tid < S_) ? sa.sS[tid] : -1e30f;
    float m = sc;
    #pragma unroll
    for (int off=32; off>0; off>>=1) m = fmaxf(m, __shfl_xor(m, off));
    float e = expf(sc - m);
    float ssum = e;
    #pragma unroll
    for (int off=32; off>0; off>>=1) ssum += __shfl_xor(ssum, off);
    sa.pS[tid] = e / ssum;
  }
  __syncthreads();
  int cg = tid & 127, sg = tid >> 7;   // 4-way s-split
  float a8[8];
  #pragma unroll
  for (int i=0;i<8;i++) a8[i] = 0.f;
  for (int s = sg; s < S_; s += 4){
    float p = sa.pS[s];
    bf16x8 e8 = *(const bf16x8*)(encb + ((size_t)s*32 + b)*C_ + cg*8);
    #pragma unroll
    for (int i=0;i<8;i++) a8[i] += p * b2f(e8[i]);
  }
  if (sg > 0){
    #pragma unroll
    for (int i=0;i<8;i++) sa.cred[sg-1][cg][i] = a8[i];
  }
  __syncthreads();
  if (sg == 0){
    union { __bf16 bb[8]; unsigned long long u[2]; } cu;
    #pragma unroll
    for (int i=0;i<8;i++){
      float v = a8[i] + sa.cred[0][cg][i] + sa.cred[1][cg][i] + sa.cred[2][cg][i];
      cu.bb[i] = (__bf16)v;
    }
    stc_u64(xa0q + (size_t)b*2560 + 512 + cg*8,     cu.u[0]);
    stc_u64(xa0q + (size_t)b*2560 + 512 + cg*8 + 4, cu.u[1]);
    stc_u64(fbt + (size_t)b*2048 + 1024 + cg*8,     cu.u[0]);
    stc_u64(fbt + (size_t)b*2048 + 1024 + cg*8 + 4, cu.u[1]);
  }
  if (embnext && tid < 64){
    union { bf16x8 v; unsigned long long u[2]; } t;
    t.v = *(const bf16x8*)(embnext + (size_t)b*512 + tid*8);
    stc_u64(xa0q + (size_t)b*2560 + tid*8,     t.u[0]);
    stc_u64(xa0q + (size_t)b*2560 + tid*8 + 4, t.u[1]);
  }
}

// ---------------- persistent decode loop (128 blocks x 512 threads) ----------------
__global__ __launch_bounds__(512) void k_loop(
    const __bf16* __restrict__ WP0, const __bf16* __restrict__ WP1,
    const float* __restrict__ b0, const float* __restrict__ b1,
    float* __restrict__ c0, float* __restrict__ c1,
    __bf16* xa0a, __bf16* xa0b, __bf16* xa1a, __bf16* xa1b,
    const __bf16* __restrict__ encb, const int* __restrict__ enc_lens,
    const __bf16* __restrict__ embb, __bf16* __restrict__ featsb,
    unsigned* bars)
{
  __shared__ SharedU su;
  int bi = blockIdx.x, tid = threadIdx.x;
  unsigned bcount = 0;
  __bf16* xa0[2] = {xa0a, xa0b};
  __bf16* xa1[2] = {xa1a, xa1b};

  for (int t = 0; t < TS; t++){
    int p = t & 1, q = p ^ 1;
    gemm_cell<2560,20>(su.g, bi, tid, xa0[p], WP0, b0, c0,
                       xa1[p], 2048, 0,
                       xa0[q], 2560, 1536,
                       (__bf16*)nullptr, 0, 0);
    grid_bar(bars, bi, ++bcount);
    gemm_cell<2048,16>(su.g, bi, tid, xa1[p], WP1, b1, c1,
                       xa1[q], 2048, 1024,
                       (__bf16*)nullptr, 0, 0,
                       featsb + (size_t)t*32*2048, 2048, 0);
    grid_bar(bars, bi, ++bcount);
    if (bi < 32)
      attn_block(su.a, bi, tid, encb, enc_lens, featsb + (size_t)t*32*2048,
                 xa0[q], (t+1 < TS) ? (embb + (size_t)(t+1)*32*EMB_) : (const __bf16*)nullptr);
    grid_bar(bars, bi, ++bcount);
  }
}

// ---------------- hproj = tanh(featsb @ WoP + bo) -> hpb (bf16 MFMA) ----------------
__global__ __launch_bounds__(256) void k_hproj_mfma(
    const __bf16* __restrict__ fb, const __bf16* __restrict__ WoP,
    const float* __restrict__ bo, __bf16* __restrict__ hpb)
{
  int nt = blockIdx.x, jb = blockIdx.y, tid = threadIdx.x;  // (47,16)
  int w = tid>>6, lane = tid&63;
  int mt = w&1, jw = w>>1;
  int am = lane&15, aq = lane>>4;
  const __bf16* aRow = fb + ((size_t)(nt*32 + mt*16 + am))*2048 + aq*8;
  int jt = jb*2 + jw;
  const __bf16* bptr = WoP + ((size_t)jt*64)*512 + lane*8;
  f32x4 acc = {0,0,0,0};
  bf16x8 ar0 = *(const bf16x8*)(aRow);
  bf16x8 br0 = *(const bf16x8*)(bptr);
  bf16x8 ar1 = *(const bf16x8*)(aRow + 32);
  bf16x8 br1 = *(const bf16x8*)(bptr + 512);
  for (int ch = 0; ch < 64; ch += 2){
    bf16x8 a0 = ar0, b0 = br0, a1 = ar1, b1 = br1;
    if (ch + 2 < 64){
      ar0 = *(const bf16x8*)(aRow + (ch+2)*32);
      br0 = *(const bf16x8*)(bptr + (size_t)(ch+2)*512);
      ar1 = *(const bf16x8*)(aRow + (ch+3)*32);
      br1 = *(const bf16x8*)(bptr + (size_t)(ch+3)*512);
    }
    acc = __builtin_amdgcn_mfma_f32_16x16x32_bf16(a0, b0, acc, 0, 0, 0);
    acc = __builtin_amdgcn_mfma_f32_16x16x32_bf16(a1, b1, acc, 0, 0, 0);
  }
  int jcol = jb*32 + jw*16 + am;
  float bv = bo[jcol];
  #pragma unroll
  for (int rg=0; rg<4; rg++){
    int m = nt*32 + mt*16 + aq*4 + rg;
    hpb[(size_t)m*512 + jcol] = (__bf16)tanhf(acc[rg] + bv);
  }
}

// ---------------- r = hpb @ P^T -> rbuf (bf16 MFMA) ----------------
__global__ __launch_bounds__(256) void k_rproj_mfma(
    const __bf16* __restrict__ hpb, const __bf16* __restrict__ PP,
    __bf16* __restrict__ rb)
{
  int nt = blockIdx.x, jb = blockIdx.y, tid = threadIdx.x;  // (47,4)
  int w = tid>>6, lane = tid&63;
  int mt = w&1, jw = w>>1;
  int am = lane&15, aq = lane>>4;
  const __bf16* aRow = hpb + ((size_t)(nt*32 + mt*16 + am))*512 + aq*8;
  int jt = jb*2 + jw;
  const __bf16* bptr = PP + ((size_t)jt*16)*512 + lane*8;
  f32x4 acc = {0,0,0,0};
  #pragma unroll
  for (int ch = 0; ch < 16; ch++){
    bf16x8 a = *(const bf16x8*)(aRow + ch*32);
    bf16x8 b = *(const bf16x8*)(bptr + (size_t)ch*512);
    acc = __builtin_amdgcn_mfma_f32_16x16x32_bf16(a, b, acc, 0, 0, 0);
  }
  int jcol = jb*32 + jw*16 + am;
  #pragma unroll
  for (int rg=0; rg<4; rg++){
    int m = nt*32 + mt*16 + aq*4 + rg;
    rb[(size_t)m*RANK_ + jcol] = (__bf16)acc[rg];
  }
}

// ---------------- vocab GEMM: grid 250 v-chunks, loop all 47 n-tiles ----------------
__global__ __launch_bounds__(256) void k_vocab2(
    const __bf16* __restrict__ rb, const __bf16* __restrict__ Eb,
    const int* __restrict__ tok,
    float* __restrict__ mpart, float* __restrict__ lpart,
    float* __restrict__ lablog)
{
  int vc = blockIdx.x, tid = threadIdx.x;
  int w = tid>>6, lane = tid&63;
  int am = lane&15, aq = lane>>4;
  int vb = vc*128 + w*32;
  bf16x8 bfr[2][4];
  #pragma unroll
  for (int vt=0; vt<2; vt++)
    #pragma unroll
    for (int ks=0; ks<4; ks++)
      bfr[vt][ks] = *(const bf16x8*)(Eb + ((size_t)(vb + vt*16 + am))*RANK_ + ks*32 + aq*8);

  __shared__ float redM[4][32], redL[4][32];
  for (int nt = 0; nt < TS; nt++){
    f32x4 acc[2][2] = {{{0,0,0,0},{0,0,0,0}},{{0,0,0,0},{0,0,0,0}}};
    #pragma unroll
    for (int mt=0; mt<2; mt++){
      #pragma unroll
      for (int ks=0; ks<4; ks++){
        bf16x8 a = *(const bf16x8*)(rb + ((size_t)(nt*32 + mt*16 + am))*RANK_ + ks*32 + aq*8);
        acc[mt][0] = __builtin_amdgcn_mfma_f32_16x16x32_bf16(a, bfr[0][ks], acc[mt][0], 0,0,0);
        acc[mt][1] = __builtin_amdgcn_mfma_f32_16x16x32_bf16(a, bfr[1][ks], acc[mt][1], 0,0,0);
      }
    }
    #pragma unroll
    for (int mt=0; mt<2; mt++){
      #pragma unroll
      for (int rg=0; rg<4; rg++){
        int row = mt*16 + aq*4 + rg;
        int n = nt*32 + row;
        int lbl = tok[row*T_ + nt + 1];
        float v0 = acc[mt][0][rg], v1 = acc[mt][1][rg];
        if (vb + am == lbl)      lablog[n] = v0;
        if (vb + 16 + am == lbl) lablog[n] = v1;
        float m = fmaxf(v0, v1);
        #pragma unroll
        for (int off=1; off<16; off<<=1) m = fmaxf(m, __shfl_xor(m, off));
        float l = expf(v0 - m) + expf(v1 - m);
        #pragma unroll
        for (int off=1; off<16; off<<=1) l += __shfl_xor(l, off);
        if (am == 0){ redM[w][row] = m; redL[w][row] = l; }
      }
    }
    __syncthreads();
    if (tid < 32){
      float M = fmaxf(fmaxf(redM[0][tid], redM[1][tid]), fmaxf(redM[2][tid], redM[3][tid]));
      float L = 0.f;
      #pragma unroll
      for (int ww=0; ww<4; ww++) L += redL[ww][tid]*expf(redM[ww][tid] - M);
      mpart[(size_t)(nt*32 + tid)*250 + vc] = M;
      lpart[(size_t)(nt*32 + tid)*250 + vc] = L;
    }
    __syncthreads();
  }
}

// ---------------- loss stage 1 ----------------
__global__ void k_loss1(const float* __restrict__ mpart, const float* __restrict__ lpart,
                        const float* __restrict__ lablog, const int* __restrict__ tgt_lens,
                        float* __restrict__ tpart){
  int t = blockIdx.x, tid = threadIdx.x;
  int row = tid >> 3, cq = tid & 7;
  int n = t*32 + row;
  float m = -1e30f;
  for (int c = cq; c < 250; c += 8) m = fmaxf(m, mpart[(size_t)n*250 + c]);
  #pragma unroll
  for (int off=1; off<8; off<<=1) m = fmaxf(m, __shfl_xor(m, off));
  float l = 0.f;
  for (int c = cq; c < 250; c += 8) l += lpart[(size_t)n*250 + c]*expf(mpart[(size_t)n*250 + c] - m);
  #pragma unroll
  for (int off=1; off<8; off<<=1) l += __shfl_xor(l, off);
  __shared__ float red[32];
  if (cq == 0)
    red[row] = (t < tgt_lens[row] - 1) ? (m + logf(l) - lablog[n]) : 0.f;
  __syncthreads();
  if (tid == 0){
    float s = 0.f;
    #pragma unroll
    for (int i=0;i<32;i++) s += red[i];
    tpart[t] = s;
  }
}

// ---------------- loss stage 2 ----------------
__global__ void k_loss2(const float* __restrict__ tpart, float* __restrict__ out){
  int tid = threadIdx.x;
  float v = (tid < TS) ? tpart[tid] : 0.f;
  #pragma unroll
  for (int off=32; off>0; off>>=1) v += __shfl_down(v, off);
  if (tid == 0) out[0] = v;
}

extern "C" void kernel_launch(void* const* d_in, const int* in_sizes, int n_in,
                              void* d_out, int out_size, void* d_ws, size_t ws_size,
                              hipStream_t stream){
  const float* enc      = (const float*)d_in[0];
  const float* es       = (const float*)d_in[1];
  const int*   tok      = (const int*)  d_in[2];
  const int*   enc_lens = (const int*)  d_in[3];
  const int*   tgt_lens = (const int*)  d_in[4];
  const float* E        = (const float*)d_in[5];
  const float* P        = (const float*)d_in[6];
  const float* W0       = (const float*)d_in[7];
  const float* U0       = (const float*)d_in[8];
  const float* b0       = (const float*)d_in[9];
  const float* W1       = (const float*)d_in[10];
  const float* U1       = (const float*)d_in[11];
  const float* b1       = (const float*)d_in[12];
  const float* Wo       = (const float*)d_in[13];
  const float* bo       = (const float*)d_in[14];
  float* out = (float*)d_out;

  float* fb = (float*)d_ws;
  size_t fo = 0;
  float* mpart = fb + fo; fo += (size_t)TS*32*250;
  float* lpart = fb + fo; fo += (size_t)TS*32*250;
  float* lab   = fb + fo; fo += (size_t)TS*32;
  float* tpart = fb + fo; fo += 64;
  float* c0    = fb + fo; fo += 32*H_;
  float* c1    = fb + fo; fo += 32*H_;
  unsigned* bars = (unsigned*)(fb + fo); fo += 512;
  __bf16* bb = (__bf16*)(fb + fo);
  size_t bo2 = 0;
  __bf16* WP0    = bb + bo2; bo2 += (size_t)4096*2560;
  __bf16* WP1    = bb + bo2; bo2 += (size_t)4096*2048;
  __bf16* encb   = bb + bo2; bo2 += (size_t)S_*32*C_;
  __bf16* embb   = bb + bo2; bo2 += (size_t)TS*32*EMB_;
  __bf16* Eb     = bb + bo2; bo2 += (size_t)VOCAB_*RANK_;
  __bf16* rbuf   = bb + bo2; bo2 += (size_t)TS*32*RANK_;
  __bf16* WoP    = bb + bo2; bo2 += (size_t)2048*512;
  __bf16* PP     = bb + bo2; bo2 += (size_t)512*128;
  __bf16* featsb = bb + bo2; bo2 += (size_t)TS*32*2048;
  __bf16* hpb    = bb + bo2; bo2 += (size_t)TS*32*EMB_;
  __bf16* xa0a   = bb + bo2; bo2 += (size_t)32*2560;
  __bf16* xa0b   = bb + bo2; bo2 += (size_t)32*2560;
  __bf16* xa1a   = bb + bo2; bo2 += (size_t)32*2048;
  __bf16* xa1b   = bb + bo2; bo2 += (size_t)32*2048;

  k_init<<<128, 256, 0, stream>>>(es, xa0a, xa1a, c0, c1, bars);
  k_cvt<<<(S_*32*C_/4 + 255)/256, 256, 0, stream>>>(enc, encb, S_*32*C_);
  k_cvt<<<(VOCAB_*RANK_/4 + 255)/256, 256, 0, stream>>>(E, Eb, VOCAB_*RANK_);
  k_embed<<<TS*32, 128, 0, stream>>>(E, P, tok, embb, xa0a);
  k_pack<<<dim3(80,64), 256, 0, stream>>>(W0, 1536, U0, WP0, 2560, 20);
  k_pack<<<dim3(64,64), 256, 0, stream>>>(W1, 1024, U1, WP1, 2048, 16);
  k_packB<<<dim3(64,32), 64, 0, stream>>>(Wo, WoP, 2048, 512, 0);
  k_packB<<<dim3(16,8), 64, 0, stream>>>(P, PP, 512, 128, 1);

  k_loop<<<NBLK, 512, 0, stream>>>(WP0, WP1, b0, b1, c0, c1,
                                   xa0a, xa0b, xa1a, xa1b,
                                   encb, enc_lens, embb, featsb, bars);

  k_hproj_mfma<<<dim3(TS,16), 256, 0, stream>>>(featsb, WoP, bo, hpb);
  k_rproj_mfma<<<dim3(TS,4), 256, 0, stream>>>(hpb, PP, rbuf);
  k_vocab2<<<250, 256, 0, stream>>>(rbuf, Eb, tok, mpart, lpart, lab);
  k_loss1<<<TS, 256, 0, stream>>>(mpart, lpart, lab, tgt_lens, tpart);
  k_loss2<<<1, 64, 0, stream>>>(tpart, out);
}